// Round 5
// baseline (314.347 us; speedup 1.0000x reference)
//
#include <hip/hip_runtime.h>
#include <math.h>

#define BB_ 256
#define NN_ 512
#define SS_ 32
#define NP1 513
#define SP1 33
#define D_IN 1024
#define D_TYPE 259
#define INV_N (1.0f/512.0f)

// front grid layout: [0,2048) keys | [2048,2304) actpre |
//                    [2304,2336) comb (16 kc x 2 rowgrp) | 2336 end
#define N_KEY 2048
#define ACT_BASE 2048
#define COMB_BASE 2304
#define END_BID 2336
#define FRONT_GRID 2337

typedef short s16x4 __attribute__((ext_vector_type(4)));
typedef short s16x8 __attribute__((ext_vector_type(8)));
typedef float f32x4 __attribute__((ext_vector_type(4)));

#if defined(__has_builtin)
#if __has_builtin(__builtin_amdgcn_rcpf)
#define FRCP(x) __builtin_amdgcn_rcpf(x)
#else
#define FRCP(x) (1.0f / (x))
#endif
#else
#define FRCP(x) (1.0f / (x))
#endif

__device__ __forceinline__ float fsig(float x) { return FRCP(1.0f + __expf(-x)); }
__device__ __forceinline__ float ftanh(float x) { return fmaf(-2.0f, FRCP(1.0f + __expf(2.0f * x)), 1.0f); }
__device__ __forceinline__ short f2bf(float f) {
    unsigned u = __float_as_uint(f);
    unsigned r = (u + 0x7FFFu + ((u >> 16) & 1u)) >> 16;
    return (short)r;
}
__device__ __forceinline__ float bf2f(short s) {
    unsigned u = ((unsigned)(unsigned short)s) << 16;
    return __uint_as_float(u);
}

// ---------------------------------------------------------------------------
// K1 fused front-end, grid 2337 x 256, __launch_bounds__(256,4) (<=128 VGPR):
//   blocks 0..2047   : pad_key bf16 = ENT x Wk^T (MFMA), 64 rows each.
//       FREE-RUNNING register stream: B packed once to 32 VGPRs, then all 16
//       A-row float4 loads issued up-front (64 VGPRs in flight), zero LDS,
//       zero barriers. Round-2's version of this died at VGPR=76 (compiler
//       serialized the loads: in-loop B global loads + no launch_bounds
//       headroom). This version hoists B and grants the register budget.
//   blocks 2048..2303: act_pre = emb0.Wfc1 + bfc1 + relu(atm.Wf + bf)
//   blocks 2304..2335: Wcomb partials, one kc chunk per block, atomicAdd
//   block  2336      : end-flag key rows
// ---------------------------------------------------------------------------
__global__ __launch_bounds__(256, 4) void front_kernel(
    const float* __restrict__ ent, const float* __restrict__ Wk,
    const float* __restrict__ bk, const float* __restrict__ endv,
    const float* __restrict__ Wemb, const float* __restrict__ bemb,
    const float* __restrict__ Wfc1, const float* __restrict__ emb0,
    const float* __restrict__ bfc1, const float* __restrict__ atm,
    const float* __restrict__ Wf, const float* __restrict__ bf,
    short* __restrict__ pkbf, float* __restrict__ WcombT,
    float* __restrict__ cbv, float* __restrict__ act_pre)
{
    __shared__ __align__(128) char u_raw[33280];
    short* a_st   = (short*)u_raw;              // comb: 128*72*2 = 18432 B
    float* wemb_s = (float*)(u_raw + 18688);    // comb: 64*33*4  = 8448 B
    float* a_lds  = (float*)u_raw;              // actpre: 16*260*4
    float* w_lds  = (float*)(u_raw + 16640);

    const int tid = threadIdx.x;
    const int bid = blockIdx.x;
    const int lane = tid & 63, w = tid >> 6;
    const int nl = lane & 15, q = lane >> 4;

    if (bid < N_KEY) {
        // ================= key MFMA: free-running register stream ===========
        const size_t rowbase = (size_t)bid * 64;
        const int rl = w * 16 + nl;                       // this lane's A row

        // ---- B fragments packed once: 32 float4 (L2/L3-hot) -> 32 VGPRs ----
        s16x8 bfr[8][2];
#pragma unroll
        for (int s = 0; s < 8; s++)
#pragma unroll
            for (int t = 0; t < 2; t++) {
                const float* src = Wk + (size_t)(t * 16 + nl) * 256 + s * 32 + q * 8;
                float4 v0 = *(const float4*)(src);
                float4 v1 = *(const float4*)(src + 4);
                s16x8 bv;
                bv[0] = f2bf(v0.x); bv[1] = f2bf(v0.y); bv[2] = f2bf(v0.z); bv[3] = f2bf(v0.w);
                bv[4] = f2bf(v1.x); bv[5] = f2bf(v1.y); bv[6] = f2bf(v1.z); bv[7] = f2bf(v1.w);
                bfr[s][t] = bv;
            }

        // ---- A row: all 16 float4 loads issued before any consumption ----
        const float* arow = ent + ((rowbase + (size_t)rl) << 8) + q * 8;
        float4 aR[16];
#pragma unroll
        for (int kk = 0; kk < 8; kk++) {
            aR[2 * kk]     = *(const float4*)(arow + kk * 32);
            aR[2 * kk + 1] = *(const float4*)(arow + kk * 32 + 4);
        }

        f32x4 acc0 = (f32x4)0.0f, acc1 = (f32x4)0.0f;
#pragma unroll
        for (int kk = 0; kk < 8; kk++) {
            float4 a0 = aR[2 * kk], a1 = aR[2 * kk + 1];
            s16x8 af;
            af[0] = f2bf(a0.x); af[1] = f2bf(a0.y); af[2] = f2bf(a0.z); af[3] = f2bf(a0.w);
            af[4] = f2bf(a1.x); af[5] = f2bf(a1.y); af[6] = f2bf(a1.z); af[7] = f2bf(a1.w);
            acc0 = __builtin_amdgcn_mfma_f32_16x16x32_bf16(af, bfr[kk][0], acc0, 0, 0, 0);
            acc1 = __builtin_amdgcn_mfma_f32_16x16x32_bf16(af, bfr[kk][1], acc1, 0, 0, 0);
        }

        float bkv0 = bk[nl], bkv1 = bk[16 + nl];
#pragma unroll
        for (int r = 0; r < 4; r++) {
            int rowg = (int)rowbase + w * 16 + q * 4 + r;
            int b = rowg >> 9, n = rowg & 511;
            pkbf[((size_t)b * NP1 + n) * 32 + nl]      = f2bf(acc0[r] + bkv0);
            pkbf[((size_t)b * NP1 + n) * 32 + 16 + nl] = f2bf(acc1[r] + bkv1);
        }
    } else if (bid < COMB_BASE) {
        // ================= actpre =================
        const int idx = bid - ACT_BASE;
        const int jt = idx & 15, bt = idx >> 4;
        const int bb = tid >> 4, jj = tid & 15;

#pragma unroll 4
        for (int r = 0; r < 16; r++) {
            a_lds[r * 260 + tid] = atm[(size_t)(bt * 16 + r) * D_TYPE + tid];
            w_lds[r * 260 + tid] = Wf[(size_t)(jt * 16 + r) * D_TYPE + tid];
            if (tid < 3) {
                a_lds[r * 260 + 256 + tid] = atm[(size_t)(bt * 16 + r) * D_TYPE + 256 + tid];
                w_lds[r * 260 + 256 + tid] = Wf[(size_t)(jt * 16 + r) * D_TYPE + 256 + tid];
            }
        }
        __syncthreads();
        float accf;
        {
            float f0 = 0.0f, f1 = 0.0f, f2 = 0.0f, f3 = 0.0f;
            const float4* ap = (const float4*)&a_lds[bb * 260];
            const float4* wp = (const float4*)&w_lds[jj * 260];
#pragma unroll 8
            for (int i4 = 0; i4 < 64; i4++) {
                float4 a = ap[i4]; float4 wv = wp[i4];
                f0 = fmaf(a.x, wv.x, f0); f1 = fmaf(a.y, wv.y, f1);
                f2 = fmaf(a.z, wv.z, f2); f3 = fmaf(a.w, wv.w, f3);
            }
            accf = (f0 + f1) + (f2 + f3);
            for (int i = 256; i < 259; i++) accf = fmaf(a_lds[bb * 260 + i], w_lds[jj * 260 + i], accf);
        }
        float c0 = 0.0f, c1 = 0.0f, c2 = 0.0f, c3 = 0.0f;
        for (int c = 0; c < 4; c++) {
            __syncthreads();
#pragma unroll
            for (int p = 0; p < 4; p++) {
                int l4 = p * 256 + tid;
                int r = l4 >> 6, k4 = l4 & 63;
                *(float4*)&a_lds[r * 260 + k4 * 4] =
                    *(const float4*)(emb0 + (size_t)(bt * 16 + r) * D_IN + c * 256 + k4 * 4);
                *(float4*)&w_lds[r * 260 + k4 * 4] =
                    *(const float4*)(Wfc1 + (size_t)(jt * 16 + r) * D_IN + c * 256 + k4 * 4);
            }
            __syncthreads();
#pragma unroll 8
            for (int k4 = 0; k4 < 64; k4++) {
                float4 a = *(const float4*)&a_lds[bb * 260 + k4 * 4];
                float4 wv = *(const float4*)&w_lds[jj * 260 + k4 * 4];
                c0 = fmaf(a.x, wv.x, c0); c1 = fmaf(a.y, wv.y, c1);
                c2 = fmaf(a.z, wv.z, c2); c3 = fmaf(a.w, wv.w, c3);
            }
        }
        float acc = (c0 + c1) + (c2 + c3);
        const int b = bt * 16 + bb, j = jt * 16 + jj;
        act_pre[b * 256 + j] = acc + bfc1[j] + fmaxf(accf + bf[j], 0.0f);
    } else if (bid < END_BID) {
        // ========= comb partial: ONE kc chunk, atomicAdd accumulate =========
        const int cb = bid - COMB_BASE;     // 0..31
        const int kc = cb >> 1;             // K chunk 0..15
        const int m0 = cb & 1;              // 128-row group of j

        // stage A: Wfc1 rows [m0*128,+128), cols [kc*64,+64) as bf16
#pragma unroll
        for (int p = 0; p < 8; p++) {
            int flat = p * 256 + tid;
            int row = flat >> 4;
            int f4 = flat & 15;
            float4 v = *(const float4*)(Wfc1 + (size_t)(m0 * 128 + row) * D_IN + kc * 64 + f4 * 4);
            s16x4 sv;
            sv[0] = f2bf(v.x); sv[1] = f2bf(v.y); sv[2] = f2bf(v.z); sv[3] = f2bf(v.w);
            *(s16x4*)&a_st[row * 72 + f4 * 4] = sv;
        }
        // stage B chunk: wemb_s[i_local][n] for i_local 0..63, n 0..32
        {
            int r = tid >> 2, c0 = tid & 3;
#pragma unroll
            for (int cc = 0; cc < 9; cc++) {
                int col = c0 + cc * 4;
                if (col < 33) {
                    float v = (col < 32) ? Wemb[(size_t)(kc * 64 + r) * 32 + col]
                                         : bemb[kc * 64 + r];
                    wemb_s[r * 33 + col] = v;
                }
            }
        }
        __syncthreads();

        f32x4 acc[2][3];
#pragma unroll
        for (int mt = 0; mt < 2; mt++)
#pragma unroll
            for (int t = 0; t < 3; t++) acc[mt][t] = (f32x4)0.0f;

#pragma unroll
        for (int ks = 0; ks < 2; ks++) {
            s16x8 bv[3];
#pragma unroll
            for (int t = 0; t < 3; t++) {
                int n = t * 16 + nl;
#pragma unroll
                for (int jj = 0; jj < 8; jj++) {
                    float v = (n < 33) ? wemb_s[(ks * 32 + q * 8 + jj) * 33 + n] : 0.0f;
                    bv[t][jj] = f2bf(v);
                }
            }
#pragma unroll
            for (int mt = 0; mt < 2; mt++) {
                s16x8 af = *(const s16x8*)&a_st[(w * 32 + mt * 16 + nl) * 72 + ks * 32 + q * 8];
#pragma unroll
                for (int t = 0; t < 3; t++)
                    acc[mt][t] = __builtin_amdgcn_mfma_f32_16x16x32_bf16(af, bv[t], acc[mt][t], 0, 0, 0);
            }
        }
#pragma unroll
        for (int mt = 0; mt < 2; mt++)
#pragma unroll
            for (int t = 0; t < 3; t++)
#pragma unroll
                for (int r = 0; r < 4; r++) {
                    int j = m0 * 128 + w * 32 + mt * 16 + q * 4 + r;
                    int n = t * 16 + nl;
                    if (n < 32) atomicAdd(&WcombT[j * 32 + n], acc[mt][t][r]);
                    else if (n == 32) atomicAdd(&cbv[j], acc[mt][t][r]);
                }
    } else {
        // ================= end-flag key rows =================
        const int k = tid & 31, b0 = tid >> 5;
        short evk = f2bf(endv[k]);
        for (int b = b0; b < BB_; b += 8)
            pkbf[((size_t)b * NP1 + 512) * 32 + k] = evk;
    }
}

// ---------------------------------------------------------------------------
// K2 back-end, grid 256 x 256: scan recurrence + logits MFMA + emb_out,
// all per-b, h kept in LDS (no global round-trip). ~77 KB LDS, phase-overlaid.
// ---------------------------------------------------------------------------
__global__ __launch_bounds__(256, 1) void back_kernel(
    const short* __restrict__ pkbf, const float* __restrict__ act_pre0,
    const int* __restrict__ sel, const float* __restrict__ avail,
    const float* __restrict__ Wfc2, const float* __restrict__ bfc2,
    const float* __restrict__ Wih, const float* __restrict__ bih,
    const float* __restrict__ bhh, const float* __restrict__ Whh,
    const float* __restrict__ WcombT, const float* __restrict__ cbv,
    const float* __restrict__ emb0, const float* __restrict__ Wemb,
    const float* __restrict__ bemb,
    float* __restrict__ logits, float* __restrict__ emb_out)
{
    __shared__ float S[19204];
    __shared__ int sel_l[SS_];
    float* rap_l  = S;                    // 8580 (33*260)           [phase A-B]
    float* red_l  = S + 8580;             // 8448 (33*256)           [phase B-C]
    float* x_l    = S + 17028;            // 1056                    [P1 scratch, C-D]
    float* cumE_l = S + 18084;            // 1056
    float* ssel_l = S + 19140;            // 32
    float* xg_l   = S;                    // 4224, overlays rap (dead post-B)
    float* h_all  = S + 4224;             // 1056, overlays rap tail
    float* m0_l   = S + 8580;             // 513, overlays red (dead post-C)
    int*   tf_l   = (int*)(S + 9093);     // 513

    const int tid = threadIdx.x;
    const int b = blockIdx.x;
    const int lane = tid & 63, w = tid >> 6;
    const int nl = lane & 15, q = lane >> 4;

    if (tid < SS_) sel_l[tid] = sel[b * SS_ + tid];

    // ---- P1: cumE prefix over selected keys ----
    {
        const int k = tid & 31, sq = tid >> 5;
        const int sq4 = sq * 4;
        int s0 = sel[b * SS_ + sq4 + 0];
        int s1 = sel[b * SS_ + sq4 + 1];
        int s2 = sel[b * SS_ + sq4 + 2];
        int s3 = sel[b * SS_ + sq4 + 3];
        float v0 = bf2f(pkbf[((size_t)b * NP1 + s0) * 32 + k]) * INV_N;
        float v1 = bf2f(pkbf[((size_t)b * NP1 + s1) * 32 + k]) * INV_N;
        float v2 = bf2f(pkbf[((size_t)b * NP1 + s2) * 32 + k]) * INV_N;
        float v3 = bf2f(pkbf[((size_t)b * NP1 + s3) * 32 + k]) * INV_N;
        float p0 = v0, p1 = p0 + v1, p2 = p1 + v2, p3 = p2 + v3;
        x_l[sq * 32 + k] = p3;
        __syncthreads();
        float off = 0.0f;
        for (int p = 0; p < 8; p++) if (p < sq) off += x_l[p * 32 + k];
        cumE_l[(sq4 + 1) * 32 + k] = off + p0;
        cumE_l[(sq4 + 2) * 32 + k] = off + p1;
        cumE_l[(sq4 + 3) * 32 + k] = off + p2;
        cumE_l[(sq4 + 4) * 32 + k] = off + p3;
        if (tid < 32) cumE_l[tid] = 0.0f;
        if (sq == 7) ssel_l[k] = off + p3;
    }
    __syncthreads();

    // ---- Phase A: rap[t][j] ----
    {
        float wcr[32];
#pragma unroll
        for (int k4 = 0; k4 < 8; k4++) {
            float4 v = *(const float4*)(WcombT + (size_t)tid * 32 + k4 * 4);
            wcr[k4*4] = v.x; wcr[k4*4+1] = v.y; wcr[k4*4+2] = v.z; wcr[k4*4+3] = v.w;
        }
        const float cbr = cbv[tid];
        const float ap0v = act_pre0[b * 256 + tid];
        for (int t = 0; t < SP1; ++t) {
            float ap = fmaf((float)t, cbr, ap0v);
            const float4* ce = (const float4*)&cumE_l[t * 32];
#pragma unroll
            for (int k4 = 0; k4 < 8; k4++) {
                float4 e = ce[k4];
                ap = fmaf(e.x, wcr[k4*4], ap);   ap = fmaf(e.y, wcr[k4*4+1], ap);
                ap = fmaf(e.z, wcr[k4*4+2], ap); ap = fmaf(e.w, wcr[k4*4+3], ap);
            }
            rap_l[t * 260 + tid] = fmaxf(ap, 0.0f);
        }
    }
    __syncthreads();

    // ---- Phase B: fc2 partials ----
    {
        const int seg = tid >> 5, i = tid & 31;
        float wfc2r[32];
#pragma unroll
        for (int i4 = 0; i4 < 8; i4++) {
            float4 v = *(const float4*)(Wfc2 + (size_t)i * 256 + seg * 32 + i4 * 4);
            wfc2r[i4*4] = v.x; wfc2r[i4*4+1] = v.y; wfc2r[i4*4+2] = v.z; wfc2r[i4*4+3] = v.w;
        }
        for (int t = 0; t < SP1; ++t) {
            float part = 0.0f;
            const float4* rp = (const float4*)&rap_l[t * 260 + seg * 32];
#pragma unroll
            for (int i4 = 0; i4 < 8; i4++) {
                float4 rv = rp[i4];
                part = fmaf(rv.x, wfc2r[i4*4], part);   part = fmaf(rv.y, wfc2r[i4*4+1], part);
                part = fmaf(rv.z, wfc2r[i4*4+2], part); part = fmaf(rv.w, wfc2r[i4*4+3], part);
            }
            red_l[t * 256 + seg * 32 + i] = part;
        }
    }
    __syncthreads();

    // ---- Phase C: reduce -> x ----
    for (int p = 0; p < 5; p++) {
        int idx = p * 256 + tid;
        if (idx < SP1 * 32) {
            int t = idx >> 5, i = idx & 31;
            float x = bfc2[i];
#pragma unroll
            for (int s = 0; s < 8; s++) x += red_l[t * 256 + s * 32 + i];
            x_l[t * 32 + i] = x;
        }
    }
    __syncthreads();

    // ---- Phase D: gates pre-h -> xg (overlays rap) ----
    {
        const int g = tid & 127, half = tid >> 7;
        float wihr[32];
#pragma unroll
        for (int k4 = 0; k4 < 8; k4++) {
            float4 v = *(const float4*)(Wih + (size_t)g * 32 + k4 * 4);
            wihr[k4*4] = v.x; wihr[k4*4+1] = v.y; wihr[k4*4+2] = v.z; wihr[k4*4+3] = v.w;
        }
        const float bihg = bih[g] + bhh[g];
        for (int t = half; t < SP1; t += 2) {
            float gg = bihg;
            const float4* xp = (const float4*)&x_l[t * 32];
#pragma unroll
            for (int k4 = 0; k4 < 8; k4++) {
                float4 xv = xp[k4];
                gg = fmaf(xv.x, wihr[k4*4], gg);   gg = fmaf(xv.y, wihr[k4*4+1], gg);
                gg = fmaf(xv.z, wihr[k4*4+2], gg); gg = fmaf(xv.w, wihr[k4*4+3], gg);
            }
            xg_l[t * 128 + g] = gg;
        }
    }
    __syncthreads();

    // ---- LSTM chain (wave 0) || mask prep (threads 64..255) ----
    if (tid < 64) {
        float whh0[32], whh1[32];
#pragma unroll
        for (int k4 = 0; k4 < 8; k4++) {
            float4 v0 = *(const float4*)(Whh + (size_t)tid * 32 + k4 * 4);
            float4 v1 = *(const float4*)(Whh + (size_t)(tid + 64) * 32 + k4 * 4);
            whh0[k4*4] = v0.x; whh0[k4*4+1] = v0.y; whh0[k4*4+2] = v0.z; whh0[k4*4+3] = v0.w;
            whh1[k4*4] = v1.x; whh1[k4*4+1] = v1.y; whh1[k4*4+2] = v1.z; whh1[k4*4+3] = v1.w;
        }
        float c = 0.0f, h = 0.0f;
        for (int t = 0; t < SP1; ++t) {
            float g0 = xg_l[t * 128 + tid];
            float g1 = xg_l[t * 128 + 64 + tid];
            if (t > 0) {
#pragma unroll
                for (int k = 0; k < 32; k++) {
                    float hk = __shfl(h, k);
                    g0 = fmaf(hk, whh0[k], g0);
                    g1 = fmaf(hk, whh1[k], g1);
                }
            }
            float og0 = __shfl_xor(g0, 32);
            float og1 = __shfl_xor(g1, 32);
            float ig = fsig(g0);
            float fg = fsig(og0);
            float gv = ftanh(g1);
            float og = fsig(og1);
            float cn = fg * c + ig * gv;
            float hn = og * ftanh(cn);
            if (tid < 32) {
                c = cn; h = hn;
                h_all[t * 32 + tid] = hn;
            }
        }
    } else {
        for (int n = tid - 64; n < NP1; n += 192) {
            float m = (n < NN_) ? avail[(size_t)b * NN_ + n] : 1.0f;
            int tf = 1000;
#pragma unroll 8
            for (int s = 0; s < SS_; s++) {
                int sv = sel_l[s];
                if (sv == n) { m = 1.0f; if (s < tf) tf = s; }
            }
            m0_l[n] = m; tf_l[n] = tf;
        }
    }
    __syncthreads();

    // ---- logits via bf16 MFMA ----
    {
        s16x8 afr[3];
#pragma unroll
        for (int mt = 0; mt < 3; mt++) {
            int row = mt * 16 + nl;
            s16x8 av;
#pragma unroll
            for (int jj = 0; jj < 8; jj++) {
                float v = (row < SP1) ? h_all[row * 32 + q * 8 + jj] : 0.0f;
                av[jj] = f2bf(v);
            }
            afr[mt] = av;
        }
        for (int tt = w; tt < 33; tt += 4) {
            int n = tt * 16 + nl;
            bool nv = n < NP1;
            s16x8 bv = nv ? *(const s16x8*)(pkbf + ((size_t)b * NP1 + n) * 32 + q * 8) : (s16x8)0;
            f32x4 acc[3];
#pragma unroll
            for (int mt = 0; mt < 3; mt++)
                acc[mt] = __builtin_amdgcn_mfma_f32_16x16x32_bf16(afr[mt], bv, (f32x4)0.0f, 0, 0, 0);
            float m0v = nv ? m0_l[n] : 0.0f;
            int tfv = nv ? tf_l[n] : 0;
#pragma unroll
            for (int mt = 0; mt < 3; mt++)
#pragma unroll
                for (int r = 0; r < 4; r++) {
                    int t = mt * 16 + q * 4 + r;
                    if (t < SP1 && nv) {
                        float mv = (t <= tfv) ? m0v : 0.0f;
                        logits[((size_t)b * SP1 + t) * NP1 + n] = acc[mt][r] - (1.0f - mv) * 1e9f;
                    }
                }
        }
    }

    // ---- emb_out ----
#pragma unroll
    for (int p = 0; p < 4; p++) {
        int i = p * 256 + tid;
        float acc = emb0[(size_t)b * D_IN + i] + 32.0f * bemb[i];
        const float* wr = Wemb + (size_t)i * 32;
#pragma unroll
        for (int k4 = 0; k4 < 8; k4++) {
            float4 wv = *(const float4*)(wr + k4 * 4);
            acc = fmaf(ssel_l[k4*4+0], wv.x, acc);
            acc = fmaf(ssel_l[k4*4+1], wv.y, acc);
            acc = fmaf(ssel_l[k4*4+2], wv.z, acc);
            acc = fmaf(ssel_l[k4*4+3], wv.w, acc);
        }
        emb_out[(size_t)b * D_IN + i] = acc;
    }
}

extern "C" void kernel_launch(void* const* d_in, const int* in_sizes, int n_in,
                              void* d_out, int out_size, void* d_ws, size_t ws_size,
                              hipStream_t stream)
{
    (void)in_sizes; (void)n_in; (void)out_size; (void)ws_size;
    const float* embedding = (const float*)d_in[0];
    const float* atm       = (const float*)d_in[1];
    const float* avail     = (const float*)d_in[2];
    const float* ent       = (const float*)d_in[3];
    const int*   sel       = (const int*)  d_in[4];
    const float* endv      = (const float*)d_in[5];
    const float* Wk   = (const float*)d_in[6];
    const float* bk   = (const float*)d_in[7];
    const float* Wf   = (const float*)d_in[8];
    const float* bf   = (const float*)d_in[9];
    const float* Wfc1 = (const float*)d_in[10];
    const float* bfc1 = (const float*)d_in[11];
    const float* Wfc2 = (const float*)d_in[12];
    const float* bfc2 = (const float*)d_in[13];
    const float* Wemb = (const float*)d_in[14];
    const float* bemb = (const float*)d_in[15];
    const float* Wih  = (const float*)d_in[16];
    const float* bih  = (const float*)d_in[17];
    const float* Whh  = (const float*)d_in[18];
    const float* bhh  = (const float*)d_in[19];

    float* ws = (float*)d_ws;
    float* act_pre = ws;                          // 65536 f
    float* WcombT  = act_pre + BB_ * 256;         // 8192 f
    float* cbv     = WcombT + 256 * 32;           // 256 f
    short* pkbf    = (short*)(cbv + 256);         // 256*513*32 shorts

    float* logits  = (float*)d_out;
    float* emb_out = logits + (size_t)BB_ * SP1 * NP1;

    // zero the comb accumulators (WcombT + cbv are contiguous: 8448 floats)
    hipMemsetAsync(WcombT, 0, (size_t)(256 * 32 + 256) * sizeof(float), stream);

    front_kernel<<<FRONT_GRID, 256, 0, stream>>>(ent, Wk, bk, endv, Wemb, bemb,
                                                 Wfc1, embedding, bfc1, atm, Wf, bf,
                                                 pkbf, WcombT, cbv, act_pre);
    back_kernel<<<BB_, 256, 0, stream>>>(pkbf, act_pre, sel, avail,
                                         Wfc2, bfc2, Wih, bih, bhh, Whh,
                                         WcombT, cbv, embedding, Wemb, bemb,
                                         logits, emb_out);
}

// Round 6
// 296.039 us; speedup vs baseline: 1.0618x; 1.0618x over previous
//
#include <hip/hip_runtime.h>
#include <math.h>

#define BB_ 256
#define NN_ 512
#define SS_ 32
#define NP1 513
#define SP1 33
#define D_IN 1024
#define D_TYPE 259
#define INV_N (1.0f/512.0f)

// front grid layout: [0,256) actpre | [256,288) comb (16 kc x 2 rowgrp) |
//                    288 end | [289, 289+2048) keys   (round-4 verified)
#define N_ACT 256
#define COMB_BASE 256
#define N_COMB 32
#define END_BID 288
#define KEY_BASE 289
#define N_KEY 2048
#define FRONT_GRID (KEY_BASE + N_KEY)

typedef short s16x4 __attribute__((ext_vector_type(4)));
typedef short s16x8 __attribute__((ext_vector_type(8)));
typedef float f32x4 __attribute__((ext_vector_type(4)));

#if defined(__has_builtin)
#if __has_builtin(__builtin_amdgcn_rcpf)
#define FRCP(x) __builtin_amdgcn_rcpf(x)
#else
#define FRCP(x) (1.0f / (x))
#endif
#else
#define FRCP(x) (1.0f / (x))
#endif

__device__ __forceinline__ float fsig(float x) { return FRCP(1.0f + __expf(-x)); }
__device__ __forceinline__ float ftanh(float x) { return fmaf(-2.0f, FRCP(1.0f + __expf(2.0f * x)), 1.0f); }
__device__ __forceinline__ short f2bf(float f) {
    unsigned u = __float_as_uint(f);
    unsigned r = (u + 0x7FFFu + ((u >> 16) & 1u)) >> 16;
    return (short)r;
}
__device__ __forceinline__ float bf2f(short s) {
    unsigned u = ((unsigned)(unsigned short)s) << 16;
    return __uint_as_float(u);
}

// ---------------------------------------------------------------------------
// K1 fused front-end (ROUND-4 VERIFIED, 76.8us): grid 2337 x 256
// ---------------------------------------------------------------------------
__global__ __launch_bounds__(256) void front_kernel(
    const float* __restrict__ ent, const float* __restrict__ Wk,
    const float* __restrict__ bk, const float* __restrict__ endv,
    const float* __restrict__ Wemb, const float* __restrict__ bemb,
    const float* __restrict__ Wfc1, const float* __restrict__ emb0,
    const float* __restrict__ bfc1, const float* __restrict__ atm,
    const float* __restrict__ Wf, const float* __restrict__ bf,
    short* __restrict__ pkbf, float* __restrict__ WcombT,
    float* __restrict__ cbv, float* __restrict__ act_pre)
{
    __shared__ __align__(128) char u_raw[33280];
    short* a_st   = (short*)u_raw;              // comb: 128*72*2 = 18432 B
    float* wemb_s = (float*)(u_raw + 18688);    // comb: 64*33*4  = 8448 B
    float* a_lds  = (float*)u_raw;              // actpre: 16*260*4
    float* w_lds  = (float*)(u_raw + 16640);

    const int tid = threadIdx.x;
    const int bid = blockIdx.x;
    const int lane = tid & 63, w = tid >> 6;
    const int nl = lane & 15, q = lane >> 4;

    if (bid >= KEY_BASE) {
        // ================= key MFMA (async-pipelined) =================
        float* kb = (float*)u_raw;
        const size_t rowbase = (size_t)(bid - KEY_BASE) * 64;

#define KSTAGE(kc_, bi_) do {                                                     \
        _Pragma("unroll")                                                         \
        for (int p_ = 0; p_ < 4; p_++) {                                          \
            int flat_ = p_ * 256 + tid;                                           \
            int row_ = flat_ >> 4, u_ = flat_ & 15;                               \
            int gf4_ = (u_ & 8) | ((u_ ^ row_) & 7);                              \
            const float* src_ = ent + (((rowbase + (size_t)row_) << 8)            \
                                       + (kc_) * 64 + gf4_ * 4);                  \
            char* dst_ = u_raw + (bi_) * 16384 + ((p_ << 8) + (w << 6)) * 16;     \
            __builtin_amdgcn_global_load_lds(                                     \
                (const __attribute__((address_space(1))) void*)src_,              \
                (__attribute__((address_space(3))) void*)dst_, 16, 0, 0);         \
        }                                                                         \
    } while (0)

        KSTAGE(0, 0);
        KSTAGE(1, 1);

        s16x8 bfr[8][2];
#pragma unroll
        for (int s = 0; s < 8; s++)
#pragma unroll
            for (int t = 0; t < 2; t++) {
                const float* src = Wk + (size_t)(t * 16 + nl) * 256 + s * 32 + q * 8;
                float4 v0 = *(const float4*)(src);
                float4 v1 = *(const float4*)(src + 4);
                s16x8 bv;
                bv[0] = f2bf(v0.x); bv[1] = f2bf(v0.y); bv[2] = f2bf(v0.z); bv[3] = f2bf(v0.w);
                bv[4] = f2bf(v1.x); bv[5] = f2bf(v1.y); bv[6] = f2bf(v1.z); bv[7] = f2bf(v1.w);
                bfr[s][t] = bv;
            }

        f32x4 acc[2];
        acc[0] = (f32x4)0.0f; acc[1] = (f32x4)0.0f;

        const int rl = w * 16 + nl;     // this lane's A row (0..63)
        const int rx = rl & 7;          // swizzle key

        asm volatile("s_waitcnt vmcnt(4)" ::: "memory");
        __builtin_amdgcn_s_barrier();
        asm volatile("" ::: "memory");

#pragma unroll
        for (int kc = 0; kc < 4; ++kc) {
            const float* kbc = kb + (kc & 1) * 4096;
#pragma unroll
            for (int ks = 0; ks < 2; ks++) {
                int s0 = ks * 8 + ((q * 2) ^ rx);
                int s1 = ks * 8 + ((q * 2 + 1) ^ rx);
                f32x4 a0 = *(const f32x4*)&kbc[rl * 64 + s0 * 4];
                f32x4 a1 = *(const f32x4*)&kbc[rl * 64 + s1 * 4];
                s16x8 af;
                af[0] = f2bf(a0[0]); af[1] = f2bf(a0[1]); af[2] = f2bf(a0[2]); af[3] = f2bf(a0[3]);
                af[4] = f2bf(a1[0]); af[5] = f2bf(a1[1]); af[6] = f2bf(a1[2]); af[7] = f2bf(a1[3]);
                acc[0] = __builtin_amdgcn_mfma_f32_16x16x32_bf16(af, bfr[kc * 2 + ks][0], acc[0], 0, 0, 0);
                acc[1] = __builtin_amdgcn_mfma_f32_16x16x32_bf16(af, bfr[kc * 2 + ks][1], acc[1], 0, 0, 0);
            }
            if (kc < 2) {
                asm volatile("s_waitcnt lgkmcnt(0)" ::: "memory");
                __builtin_amdgcn_s_barrier();
                asm volatile("" ::: "memory");
                KSTAGE(kc + 2, kc & 1);
                asm volatile("s_waitcnt vmcnt(4)" ::: "memory");
                __builtin_amdgcn_s_barrier();
                asm volatile("" ::: "memory");
            } else if (kc == 2) {
                asm volatile("s_waitcnt vmcnt(0)" ::: "memory");
                __builtin_amdgcn_s_barrier();
                asm volatile("" ::: "memory");
            }
        }
#undef KSTAGE

        float bkv0 = bk[nl], bkv1 = bk[16 + nl];
#pragma unroll
        for (int t = 0; t < 2; t++)
#pragma unroll
            for (int r = 0; r < 4; r++) {
                int rowg = (int)rowbase + w * 16 + q * 4 + r;
                int b = rowg >> 9, n = rowg & 511;
                pkbf[((size_t)b * NP1 + n) * 32 + t * 16 + nl] =
                    f2bf(acc[t][r] + (t ? bkv1 : bkv0));
            }
    } else if (bid < N_ACT) {
        // ================= actpre =================
        const int idx = bid;
        const int jt = idx & 15, bt = idx >> 4;
        const int bb = tid >> 4, jj = tid & 15;

#pragma unroll 4
        for (int r = 0; r < 16; r++) {
            a_lds[r * 260 + tid] = atm[(size_t)(bt * 16 + r) * D_TYPE + tid];
            w_lds[r * 260 + tid] = Wf[(size_t)(jt * 16 + r) * D_TYPE + tid];
            if (tid < 3) {
                a_lds[r * 260 + 256 + tid] = atm[(size_t)(bt * 16 + r) * D_TYPE + 256 + tid];
                w_lds[r * 260 + 256 + tid] = Wf[(size_t)(jt * 16 + r) * D_TYPE + 256 + tid];
            }
        }
        __syncthreads();
        float accf;
        {
            float f0 = 0.0f, f1 = 0.0f, f2 = 0.0f, f3 = 0.0f;
            const float4* ap = (const float4*)&a_lds[bb * 260];
            const float4* wp = (const float4*)&w_lds[jj * 260];
#pragma unroll 8
            for (int i4 = 0; i4 < 64; i4++) {
                float4 a = ap[i4]; float4 wv = wp[i4];
                f0 = fmaf(a.x, wv.x, f0); f1 = fmaf(a.y, wv.y, f1);
                f2 = fmaf(a.z, wv.z, f2); f3 = fmaf(a.w, wv.w, f3);
            }
            accf = (f0 + f1) + (f2 + f3);
            for (int i = 256; i < 259; i++) accf = fmaf(a_lds[bb * 260 + i], w_lds[jj * 260 + i], accf);
        }
        float c0 = 0.0f, c1 = 0.0f, c2 = 0.0f, c3 = 0.0f;
        for (int c = 0; c < 4; c++) {
            __syncthreads();
#pragma unroll
            for (int p = 0; p < 4; p++) {
                int l4 = p * 256 + tid;
                int r = l4 >> 6, k4 = l4 & 63;
                *(float4*)&a_lds[r * 260 + k4 * 4] =
                    *(const float4*)(emb0 + (size_t)(bt * 16 + r) * D_IN + c * 256 + k4 * 4);
                *(float4*)&w_lds[r * 260 + k4 * 4] =
                    *(const float4*)(Wfc1 + (size_t)(jt * 16 + r) * D_IN + c * 256 + k4 * 4);
            }
            __syncthreads();
#pragma unroll 8
            for (int k4 = 0; k4 < 64; k4++) {
                float4 a = *(const float4*)&a_lds[bb * 260 + k4 * 4];
                float4 wv = *(const float4*)&w_lds[jj * 260 + k4 * 4];
                c0 = fmaf(a.x, wv.x, c0); c1 = fmaf(a.y, wv.y, c1);
                c2 = fmaf(a.z, wv.z, c2); c3 = fmaf(a.w, wv.w, c3);
            }
        }
        float acc = (c0 + c1) + (c2 + c3);
        const int b = bt * 16 + bb, j = jt * 16 + jj;
        act_pre[b * 256 + j] = acc + bfc1[j] + fmaxf(accf + bf[j], 0.0f);
    } else if (bid < END_BID) {
        // ========= comb partial: ONE kc chunk, atomicAdd accumulate =========
        const int cb = bid - COMB_BASE;     // 0..31
        const int kc = cb >> 1;             // K chunk 0..15
        const int m0 = cb & 1;              // 128-row group of j

#pragma unroll
        for (int p = 0; p < 8; p++) {
            int flat = p * 256 + tid;
            int row = flat >> 4;
            int f4 = flat & 15;
            float4 v = *(const float4*)(Wfc1 + (size_t)(m0 * 128 + row) * D_IN + kc * 64 + f4 * 4);
            s16x4 sv;
            sv[0] = f2bf(v.x); sv[1] = f2bf(v.y); sv[2] = f2bf(v.z); sv[3] = f2bf(v.w);
            *(s16x4*)&a_st[row * 72 + f4 * 4] = sv;
        }
        {
            int r = tid >> 2, c0 = tid & 3;
#pragma unroll
            for (int cc = 0; cc < 9; cc++) {
                int col = c0 + cc * 4;
                if (col < 33) {
                    float v = (col < 32) ? Wemb[(size_t)(kc * 64 + r) * 32 + col]
                                         : bemb[kc * 64 + r];
                    wemb_s[r * 33 + col] = v;
                }
            }
        }
        __syncthreads();

        f32x4 acc[2][3];
#pragma unroll
        for (int mt = 0; mt < 2; mt++)
#pragma unroll
            for (int t = 0; t < 3; t++) acc[mt][t] = (f32x4)0.0f;

#pragma unroll
        for (int ks = 0; ks < 2; ks++) {
            s16x8 bv[3];
#pragma unroll
            for (int t = 0; t < 3; t++) {
                int n = t * 16 + nl;
#pragma unroll
                for (int jj = 0; jj < 8; jj++) {
                    float v = (n < 33) ? wemb_s[(ks * 32 + q * 8 + jj) * 33 + n] : 0.0f;
                    bv[t][jj] = f2bf(v);
                }
            }
#pragma unroll
            for (int mt = 0; mt < 2; mt++) {
                s16x8 af = *(const s16x8*)&a_st[(w * 32 + mt * 16 + nl) * 72 + ks * 32 + q * 8];
#pragma unroll
                for (int t = 0; t < 3; t++)
                    acc[mt][t] = __builtin_amdgcn_mfma_f32_16x16x32_bf16(af, bv[t], acc[mt][t], 0, 0, 0);
            }
        }
#pragma unroll
        for (int mt = 0; mt < 2; mt++)
#pragma unroll
            for (int t = 0; t < 3; t++)
#pragma unroll
                for (int r = 0; r < 4; r++) {
                    int j = m0 * 128 + w * 32 + mt * 16 + q * 4 + r;
                    int n = t * 16 + nl;
                    if (n < 32) atomicAdd(&WcombT[j * 32 + n], acc[mt][t][r]);
                    else if (n == 32) atomicAdd(&cbv[j], acc[mt][t][r]);
                }
    } else {
        // ================= end-flag key rows =================
        const int k = tid & 31, b0 = tid >> 5;
        short evk = f2bf(endv[k]);
        for (int b = b0; b < BB_; b += 8)
            pkbf[((size_t)b * NP1 + 512) * 32 + k] = evk;
    }
}

// ---------------------------------------------------------------------------
// K2 back-end, grid 256 x 512 (WIDENED from 256 threads): scan recurrence +
// logits MFMA + emb_out per-b. Same 77KB LDS and per-output math; every
// data-parallel phase's t-loop is split across the extra 4 waves:
//   A/B: 2-way t-split | D: 4-way | logits: tt stride 8 | C/emb_out re-indexed
//   P1 duplicated benignly across halves | LSTM stays wave-0, 448 mask threads
// Rationale: grid is pinned at 1 block/CU (B=256); doubling waves/block is the
// only way to raise occupancy 12.5% -> 25% and halve phase latency exposure.
// ---------------------------------------------------------------------------
__global__ __launch_bounds__(512, 1) void back_kernel(
    const short* __restrict__ pkbf, const float* __restrict__ act_pre0,
    const int* __restrict__ sel, const float* __restrict__ avail,
    const float* __restrict__ Wfc2, const float* __restrict__ bfc2,
    const float* __restrict__ Wih, const float* __restrict__ bih,
    const float* __restrict__ bhh, const float* __restrict__ Whh,
    const float* __restrict__ WcombT, const float* __restrict__ cbv,
    const float* __restrict__ emb0, const float* __restrict__ Wemb,
    const float* __restrict__ bemb,
    float* __restrict__ logits, float* __restrict__ emb_out)
{
    __shared__ float S[19204];
    __shared__ int sel_l[SS_];
    float* rap_l  = S;                    // 8580 (33*260)           [phase A-B]
    float* red_l  = S + 8580;             // 8448 (33*256)           [phase B-C]
    float* x_l    = S + 17028;            // 1056                    [P1 scratch, C-D]
    float* cumE_l = S + 18084;            // 1056
    float* ssel_l = S + 19140;            // 32
    float* xg_l   = S;                    // 4224, overlays rap (dead post-B)
    float* h_all  = S + 4224;             // 1056, overlays rap tail
    float* m0_l   = S + 8580;             // 513, overlays red (dead post-C)
    int*   tf_l   = (int*)(S + 9093);     // 513

    const int tid = threadIdx.x;
    const int b = blockIdx.x;
    const int lane = tid & 63, w = tid >> 6;       // w: 0..7
    const int nl = lane & 15, q = lane >> 4;

    if (tid < SS_) sel_l[tid] = sel[b * SS_ + tid];

    // ---- P1: cumE prefix over selected keys (both halves duplicate; all
    //      writes are identical values, so the WAW races are benign) ----
    {
        const int k = tid & 31, sq = (tid >> 5) & 7;
        const int sq4 = sq * 4;
        int s0 = sel[b * SS_ + sq4 + 0];
        int s1 = sel[b * SS_ + sq4 + 1];
        int s2 = sel[b * SS_ + sq4 + 2];
        int s3 = sel[b * SS_ + sq4 + 3];
        float v0 = bf2f(pkbf[((size_t)b * NP1 + s0) * 32 + k]) * INV_N;
        float v1 = bf2f(pkbf[((size_t)b * NP1 + s1) * 32 + k]) * INV_N;
        float v2 = bf2f(pkbf[((size_t)b * NP1 + s2) * 32 + k]) * INV_N;
        float v3 = bf2f(pkbf[((size_t)b * NP1 + s3) * 32 + k]) * INV_N;
        float p0 = v0, p1 = p0 + v1, p2 = p1 + v2, p3 = p2 + v3;
        x_l[sq * 32 + k] = p3;
        __syncthreads();
        float off = 0.0f;
        for (int p = 0; p < 8; p++) if (p < sq) off += x_l[p * 32 + k];
        cumE_l[(sq4 + 1) * 32 + k] = off + p0;
        cumE_l[(sq4 + 2) * 32 + k] = off + p1;
        cumE_l[(sq4 + 3) * 32 + k] = off + p2;
        cumE_l[(sq4 + 4) * 32 + k] = off + p3;
        if (tid < 32) cumE_l[tid] = 0.0f;
        if (sq == 7) ssel_l[k] = off + p3;
    }
    __syncthreads();

    // ---- Phase A: rap[t][j], 2-way t-split across halves ----
    {
        const int j = tid & 255, half = tid >> 8;
        float wcr[32];
#pragma unroll
        for (int k4 = 0; k4 < 8; k4++) {
            float4 v = *(const float4*)(WcombT + (size_t)j * 32 + k4 * 4);
            wcr[k4*4] = v.x; wcr[k4*4+1] = v.y; wcr[k4*4+2] = v.z; wcr[k4*4+3] = v.w;
        }
        const float cbr = cbv[j];
        const float ap0v = act_pre0[b * 256 + j];
        for (int t = half; t < SP1; t += 2) {
            float ap = fmaf((float)t, cbr, ap0v);
            const float4* ce = (const float4*)&cumE_l[t * 32];
#pragma unroll
            for (int k4 = 0; k4 < 8; k4++) {
                float4 e = ce[k4];
                ap = fmaf(e.x, wcr[k4*4], ap);   ap = fmaf(e.y, wcr[k4*4+1], ap);
                ap = fmaf(e.z, wcr[k4*4+2], ap); ap = fmaf(e.w, wcr[k4*4+3], ap);
            }
            rap_l[t * 260 + j] = fmaxf(ap, 0.0f);
        }
    }
    __syncthreads();

    // ---- Phase B: fc2 partials, 2-way t-split ----
    {
        const int i = tid & 31, seg = (tid >> 5) & 7, half = tid >> 8;
        float wfc2r[32];
#pragma unroll
        for (int i4 = 0; i4 < 8; i4++) {
            float4 v = *(const float4*)(Wfc2 + (size_t)i * 256 + seg * 32 + i4 * 4);
            wfc2r[i4*4] = v.x; wfc2r[i4*4+1] = v.y; wfc2r[i4*4+2] = v.z; wfc2r[i4*4+3] = v.w;
        }
        for (int t = half; t < SP1; t += 2) {
            float part = 0.0f;
            const float4* rp = (const float4*)&rap_l[t * 260 + seg * 32];
#pragma unroll
            for (int i4 = 0; i4 < 8; i4++) {
                float4 rv = rp[i4];
                part = fmaf(rv.x, wfc2r[i4*4], part);   part = fmaf(rv.y, wfc2r[i4*4+1], part);
                part = fmaf(rv.z, wfc2r[i4*4+2], part); part = fmaf(rv.w, wfc2r[i4*4+3], part);
            }
            red_l[t * 256 + seg * 32 + i] = part;
        }
    }
    __syncthreads();

    // ---- Phase C: reduce -> x ----
    for (int p = 0; p < 3; p++) {
        int idx = p * 512 + tid;
        if (idx < SP1 * 32) {
            int t = idx >> 5, i = idx & 31;
            float x = bfc2[i];
#pragma unroll
            for (int s = 0; s < 8; s++) x += red_l[t * 256 + s * 32 + i];
            x_l[t * 32 + i] = x;
        }
    }
    __syncthreads();

    // ---- Phase D: gates pre-h -> xg (overlays rap), 4-way t-split ----
    {
        const int g = tid & 127, qtr = tid >> 7;     // qtr: 0..3
        float wihr[32];
#pragma unroll
        for (int k4 = 0; k4 < 8; k4++) {
            float4 v = *(const float4*)(Wih + (size_t)g * 32 + k4 * 4);
            wihr[k4*4] = v.x; wihr[k4*4+1] = v.y; wihr[k4*4+2] = v.z; wihr[k4*4+3] = v.w;
        }
        const float bihg = bih[g] + bhh[g];
        for (int t = qtr; t < SP1; t += 4) {
            float gg = bihg;
            const float4* xp = (const float4*)&x_l[t * 32];
#pragma unroll
            for (int k4 = 0; k4 < 8; k4++) {
                float4 xv = xp[k4];
                gg = fmaf(xv.x, wihr[k4*4], gg);   gg = fmaf(xv.y, wihr[k4*4+1], gg);
                gg = fmaf(xv.z, wihr[k4*4+2], gg); gg = fmaf(xv.w, wihr[k4*4+3], gg);
            }
            xg_l[t * 128 + g] = gg;
        }
    }
    __syncthreads();

    // ---- LSTM chain (wave 0) || mask prep (threads 64..511) ----
    if (tid < 64) {
        float whh0[32], whh1[32];
#pragma unroll
        for (int k4 = 0; k4 < 8; k4++) {
            float4 v0 = *(const float4*)(Whh + (size_t)tid * 32 + k4 * 4);
            float4 v1 = *(const float4*)(Whh + (size_t)(tid + 64) * 32 + k4 * 4);
            whh0[k4*4] = v0.x; whh0[k4*4+1] = v0.y; whh0[k4*4+2] = v0.z; whh0[k4*4+3] = v0.w;
            whh1[k4*4] = v1.x; whh1[k4*4+1] = v1.y; whh1[k4*4+2] = v1.z; whh1[k4*4+3] = v1.w;
        }
        float c = 0.0f, h = 0.0f;
        for (int t = 0; t < SP1; ++t) {
            float g0 = xg_l[t * 128 + tid];
            float g1 = xg_l[t * 128 + 64 + tid];
            if (t > 0) {
#pragma unroll
                for (int k = 0; k < 32; k++) {
                    float hk = __shfl(h, k);
                    g0 = fmaf(hk, whh0[k], g0);
                    g1 = fmaf(hk, whh1[k], g1);
                }
            }
            float og0 = __shfl_xor(g0, 32);
            float og1 = __shfl_xor(g1, 32);
            float ig = fsig(g0);
            float fg = fsig(og0);
            float gv = ftanh(g1);
            float og = fsig(og1);
            float cn = fg * c + ig * gv;
            float hn = og * ftanh(cn);
            if (tid < 32) {
                c = cn; h = hn;
                h_all[t * 32 + tid] = hn;
            }
        }
    } else {
        for (int n = tid - 64; n < NP1; n += 448) {
            float m = (n < NN_) ? avail[(size_t)b * NN_ + n] : 1.0f;
            int tf = 1000;
#pragma unroll 8
            for (int s = 0; s < SS_; s++) {
                int sv = sel_l[s];
                if (sv == n) { m = 1.0f; if (s < tf) tf = s; }
            }
            m0_l[n] = m; tf_l[n] = tf;
        }
    }
    __syncthreads();

    // ---- logits via bf16 MFMA (8 waves, tt stride 8) ----
    {
        s16x8 afr[3];
#pragma unroll
        for (int mt = 0; mt < 3; mt++) {
            int row = mt * 16 + nl;
            s16x8 av;
#pragma unroll
            for (int jj = 0; jj < 8; jj++) {
                float v = (row < SP1) ? h_all[row * 32 + q * 8 + jj] : 0.0f;
                av[jj] = f2bf(v);
            }
            afr[mt] = av;
        }
        for (int tt = w; tt < 33; tt += 8) {
            int n = tt * 16 + nl;
            bool nv = n < NP1;
            s16x8 bv = nv ? *(const s16x8*)(pkbf + ((size_t)b * NP1 + n) * 32 + q * 8) : (s16x8)0;
            f32x4 acc[3];
#pragma unroll
            for (int mt = 0; mt < 3; mt++)
                acc[mt] = __builtin_amdgcn_mfma_f32_16x16x32_bf16(afr[mt], bv, (f32x4)0.0f, 0, 0, 0);
            float m0v = nv ? m0_l[n] : 0.0f;
            int tfv = nv ? tf_l[n] : 0;
#pragma unroll
            for (int mt = 0; mt < 3; mt++)
#pragma unroll
                for (int r = 0; r < 4; r++) {
                    int t = mt * 16 + q * 4 + r;
                    if (t < SP1 && nv) {
                        float mv = (t <= tfv) ? m0v : 0.0f;
                        logits[((size_t)b * SP1 + t) * NP1 + n] = acc[mt][r] - (1.0f - mv) * 1e9f;
                    }
                }
        }
    }

    // ---- emb_out ----
#pragma unroll
    for (int p = 0; p < 2; p++) {
        int i = p * 512 + tid;
        float acc = emb0[(size_t)b * D_IN + i] + 32.0f * bemb[i];
        const float* wr = Wemb + (size_t)i * 32;
#pragma unroll
        for (int k4 = 0; k4 < 8; k4++) {
            float4 wv = *(const float4*)(wr + k4 * 4);
            acc = fmaf(ssel_l[k4*4+0], wv.x, acc);
            acc = fmaf(ssel_l[k4*4+1], wv.y, acc);
            acc = fmaf(ssel_l[k4*4+2], wv.z, acc);
            acc = fmaf(ssel_l[k4*4+3], wv.w, acc);
        }
        emb_out[(size_t)b * D_IN + i] = acc;
    }
}

extern "C" void kernel_launch(void* const* d_in, const int* in_sizes, int n_in,
                              void* d_out, int out_size, void* d_ws, size_t ws_size,
                              hipStream_t stream)
{
    (void)in_sizes; (void)n_in; (void)out_size; (void)ws_size;
    const float* embedding = (const float*)d_in[0];
    const float* atm       = (const float*)d_in[1];
    const float* avail     = (const float*)d_in[2];
    const float* ent       = (const float*)d_in[3];
    const int*   sel       = (const int*)  d_in[4];
    const float* endv      = (const float*)d_in[5];
    const float* Wk   = (const float*)d_in[6];
    const float* bk   = (const float*)d_in[7];
    const float* Wf   = (const float*)d_in[8];
    const float* bf   = (const float*)d_in[9];
    const float* Wfc1 = (const float*)d_in[10];
    const float* bfc1 = (const float*)d_in[11];
    const float* Wfc2 = (const float*)d_in[12];
    const float* bfc2 = (const float*)d_in[13];
    const float* Wemb = (const float*)d_in[14];
    const float* bemb = (const float*)d_in[15];
    const float* Wih  = (const float*)d_in[16];
    const float* bih  = (const float*)d_in[17];
    const float* Whh  = (const float*)d_in[18];
    const float* bhh  = (const float*)d_in[19];

    float* ws = (float*)d_ws;
    float* act_pre = ws;                          // 65536 f
    float* WcombT  = act_pre + BB_ * 256;         // 8192 f
    float* cbv     = WcombT + 256 * 32;           // 256 f
    short* pkbf    = (short*)(cbv + 256);         // 256*513*32 shorts

    float* logits  = (float*)d_out;
    float* emb_out = logits + (size_t)BB_ * SP1 * NP1;

    // zero the comb accumulators (WcombT + cbv are contiguous: 8448 floats)
    hipMemsetAsync(WcombT, 0, (size_t)(256 * 32 + 256) * sizeof(float), stream);

    front_kernel<<<FRONT_GRID, 256, 0, stream>>>(ent, Wk, bk, endv, Wemb, bemb,
                                                 Wfc1, embedding, bfc1, atm, Wf, bf,
                                                 pkbf, WcombT, cbv, act_pre);
    back_kernel<<<BB_, 512, 0, stream>>>(pkbf, act_pre, sel, avail,
                                         Wfc2, bfc2, Wih, bih, bhh, Whh,
                                         WcombT, cbv, embedding, Wemb, bemb,
                                         logits, emb_out);
}

// Round 7
// 289.701 us; speedup vs baseline: 1.0851x; 1.0219x over previous
//
#include <hip/hip_runtime.h>
#include <math.h>

#define BB_ 256
#define NN_ 512
#define SS_ 32
#define NP1 513
#define SP1 33
#define D_IN 1024
#define D_TYPE 259
#define INV_N (1.0f/512.0f)

// front grid layout: [0,256) actpre | [256,288) comb (16 kc x 2 rowgrp) |
//                    288 end | [289, 289+2048) keys   (round-4 verified)
#define N_ACT 256
#define COMB_BASE 256
#define N_COMB 32
#define END_BID 288
#define KEY_BASE 289
#define N_KEY 2048
#define FRONT_GRID (KEY_BASE + N_KEY)

typedef short s16x4 __attribute__((ext_vector_type(4)));
typedef short s16x8 __attribute__((ext_vector_type(8)));
typedef float f32x4 __attribute__((ext_vector_type(4)));

#if defined(__has_builtin)
#if __has_builtin(__builtin_amdgcn_rcpf)
#define FRCP(x) __builtin_amdgcn_rcpf(x)
#else
#define FRCP(x) (1.0f / (x))
#endif
#else
#define FRCP(x) (1.0f / (x))
#endif

__device__ __forceinline__ float fsig(float x) { return FRCP(1.0f + __expf(-x)); }
__device__ __forceinline__ float ftanh(float x) { return fmaf(-2.0f, FRCP(1.0f + __expf(2.0f * x)), 1.0f); }
__device__ __forceinline__ short f2bf(float f) {
    unsigned u = __float_as_uint(f);
    unsigned r = (u + 0x7FFFu + ((u >> 16) & 1u)) >> 16;
    return (short)r;
}
__device__ __forceinline__ float bf2f(short s) {
    unsigned u = ((unsigned)(unsigned short)s) << 16;
    return __uint_as_float(u);
}

// ---------------------------------------------------------------------------
// K1 fused front-end (ROUND-4 VERIFIED, 76.8us): grid 2337 x 256
// ---------------------------------------------------------------------------
__global__ __launch_bounds__(256) void front_kernel(
    const float* __restrict__ ent, const float* __restrict__ Wk,
    const float* __restrict__ bk, const float* __restrict__ endv,
    const float* __restrict__ Wemb, const float* __restrict__ bemb,
    const float* __restrict__ Wfc1, const float* __restrict__ emb0,
    const float* __restrict__ bfc1, const float* __restrict__ atm,
    const float* __restrict__ Wf, const float* __restrict__ bf,
    short* __restrict__ pkbf, float* __restrict__ WcombT,
    float* __restrict__ cbv, float* __restrict__ act_pre)
{
    __shared__ __align__(128) char u_raw[33280];
    short* a_st   = (short*)u_raw;              // comb: 128*72*2 = 18432 B
    float* wemb_s = (float*)(u_raw + 18688);    // comb: 64*33*4  = 8448 B
    float* a_lds  = (float*)u_raw;              // actpre: 16*260*4
    float* w_lds  = (float*)(u_raw + 16640);

    const int tid = threadIdx.x;
    const int bid = blockIdx.x;
    const int lane = tid & 63, w = tid >> 6;
    const int nl = lane & 15, q = lane >> 4;

    if (bid >= KEY_BASE) {
        // ================= key MFMA (async-pipelined) =================
        float* kb = (float*)u_raw;
        const size_t rowbase = (size_t)(bid - KEY_BASE) * 64;

#define KSTAGE(kc_, bi_) do {                                                     \
        _Pragma("unroll")                                                         \
        for (int p_ = 0; p_ < 4; p_++) {                                          \
            int flat_ = p_ * 256 + tid;                                           \
            int row_ = flat_ >> 4, u_ = flat_ & 15;                               \
            int gf4_ = (u_ & 8) | ((u_ ^ row_) & 7);                              \
            const float* src_ = ent + (((rowbase + (size_t)row_) << 8)            \
                                       + (kc_) * 64 + gf4_ * 4);                  \
            char* dst_ = u_raw + (bi_) * 16384 + ((p_ << 8) + (w << 6)) * 16;     \
            __builtin_amdgcn_global_load_lds(                                     \
                (const __attribute__((address_space(1))) void*)src_,              \
                (__attribute__((address_space(3))) void*)dst_, 16, 0, 0);         \
        }                                                                         \
    } while (0)

        KSTAGE(0, 0);
        KSTAGE(1, 1);

        s16x8 bfr[8][2];
#pragma unroll
        for (int s = 0; s < 8; s++)
#pragma unroll
            for (int t = 0; t < 2; t++) {
                const float* src = Wk + (size_t)(t * 16 + nl) * 256 + s * 32 + q * 8;
                float4 v0 = *(const float4*)(src);
                float4 v1 = *(const float4*)(src + 4);
                s16x8 bv;
                bv[0] = f2bf(v0.x); bv[1] = f2bf(v0.y); bv[2] = f2bf(v0.z); bv[3] = f2bf(v0.w);
                bv[4] = f2bf(v1.x); bv[5] = f2bf(v1.y); bv[6] = f2bf(v1.z); bv[7] = f2bf(v1.w);
                bfr[s][t] = bv;
            }

        f32x4 acc[2];
        acc[0] = (f32x4)0.0f; acc[1] = (f32x4)0.0f;

        const int rl = w * 16 + nl;     // this lane's A row (0..63)
        const int rx = rl & 7;          // swizzle key

        asm volatile("s_waitcnt vmcnt(4)" ::: "memory");
        __builtin_amdgcn_s_barrier();
        asm volatile("" ::: "memory");

#pragma unroll
        for (int kc = 0; kc < 4; ++kc) {
            const float* kbc = kb + (kc & 1) * 4096;
#pragma unroll
            for (int ks = 0; ks < 2; ks++) {
                int s0 = ks * 8 + ((q * 2) ^ rx);
                int s1 = ks * 8 + ((q * 2 + 1) ^ rx);
                f32x4 a0 = *(const f32x4*)&kbc[rl * 64 + s0 * 4];
                f32x4 a1 = *(const f32x4*)&kbc[rl * 64 + s1 * 4];
                s16x8 af;
                af[0] = f2bf(a0[0]); af[1] = f2bf(a0[1]); af[2] = f2bf(a0[2]); af[3] = f2bf(a0[3]);
                af[4] = f2bf(a1[0]); af[5] = f2bf(a1[1]); af[6] = f2bf(a1[2]); af[7] = f2bf(a1[3]);
                acc[0] = __builtin_amdgcn_mfma_f32_16x16x32_bf16(af, bfr[kc * 2 + ks][0], acc[0], 0, 0, 0);
                acc[1] = __builtin_amdgcn_mfma_f32_16x16x32_bf16(af, bfr[kc * 2 + ks][1], acc[1], 0, 0, 0);
            }
            if (kc < 2) {
                asm volatile("s_waitcnt lgkmcnt(0)" ::: "memory");
                __builtin_amdgcn_s_barrier();
                asm volatile("" ::: "memory");
                KSTAGE(kc + 2, kc & 1);
                asm volatile("s_waitcnt vmcnt(4)" ::: "memory");
                __builtin_amdgcn_s_barrier();
                asm volatile("" ::: "memory");
            } else if (kc == 2) {
                asm volatile("s_waitcnt vmcnt(0)" ::: "memory");
                __builtin_amdgcn_s_barrier();
                asm volatile("" ::: "memory");
            }
        }
#undef KSTAGE

        float bkv0 = bk[nl], bkv1 = bk[16 + nl];
#pragma unroll
        for (int t = 0; t < 2; t++)
#pragma unroll
            for (int r = 0; r < 4; r++) {
                int rowg = (int)rowbase + w * 16 + q * 4 + r;
                int b = rowg >> 9, n = rowg & 511;
                pkbf[((size_t)b * NP1 + n) * 32 + t * 16 + nl] =
                    f2bf(acc[t][r] + (t ? bkv1 : bkv0));
            }
    } else if (bid < N_ACT) {
        // ================= actpre =================
        const int idx = bid;
        const int jt = idx & 15, bt = idx >> 4;
        const int bb = tid >> 4, jj = tid & 15;

#pragma unroll 4
        for (int r = 0; r < 16; r++) {
            a_lds[r * 260 + tid] = atm[(size_t)(bt * 16 + r) * D_TYPE + tid];
            w_lds[r * 260 + tid] = Wf[(size_t)(jt * 16 + r) * D_TYPE + tid];
            if (tid < 3) {
                a_lds[r * 260 + 256 + tid] = atm[(size_t)(bt * 16 + r) * D_TYPE + 256 + tid];
                w_lds[r * 260 + 256 + tid] = Wf[(size_t)(jt * 16 + r) * D_TYPE + 256 + tid];
            }
        }
        __syncthreads();
        float accf;
        {
            float f0 = 0.0f, f1 = 0.0f, f2 = 0.0f, f3 = 0.0f;
            const float4* ap = (const float4*)&a_lds[bb * 260];
            const float4* wp = (const float4*)&w_lds[jj * 260];
#pragma unroll 8
            for (int i4 = 0; i4 < 64; i4++) {
                float4 a = ap[i4]; float4 wv = wp[i4];
                f0 = fmaf(a.x, wv.x, f0); f1 = fmaf(a.y, wv.y, f1);
                f2 = fmaf(a.z, wv.z, f2); f3 = fmaf(a.w, wv.w, f3);
            }
            accf = (f0 + f1) + (f2 + f3);
            for (int i = 256; i < 259; i++) accf = fmaf(a_lds[bb * 260 + i], w_lds[jj * 260 + i], accf);
        }
        float c0 = 0.0f, c1 = 0.0f, c2 = 0.0f, c3 = 0.0f;
        for (int c = 0; c < 4; c++) {
            __syncthreads();
#pragma unroll
            for (int p = 0; p < 4; p++) {
                int l4 = p * 256 + tid;
                int r = l4 >> 6, k4 = l4 & 63;
                *(float4*)&a_lds[r * 260 + k4 * 4] =
                    *(const float4*)(emb0 + (size_t)(bt * 16 + r) * D_IN + c * 256 + k4 * 4);
                *(float4*)&w_lds[r * 260 + k4 * 4] =
                    *(const float4*)(Wfc1 + (size_t)(jt * 16 + r) * D_IN + c * 256 + k4 * 4);
            }
            __syncthreads();
#pragma unroll 8
            for (int k4 = 0; k4 < 64; k4++) {
                float4 a = *(const float4*)&a_lds[bb * 260 + k4 * 4];
                float4 wv = *(const float4*)&w_lds[jj * 260 + k4 * 4];
                c0 = fmaf(a.x, wv.x, c0); c1 = fmaf(a.y, wv.y, c1);
                c2 = fmaf(a.z, wv.z, c2); c3 = fmaf(a.w, wv.w, c3);
            }
        }
        float acc = (c0 + c1) + (c2 + c3);
        const int b = bt * 16 + bb, j = jt * 16 + jj;
        act_pre[b * 256 + j] = acc + bfc1[j] + fmaxf(accf + bf[j], 0.0f);
    } else if (bid < END_BID) {
        // ========= comb partial: ONE kc chunk, atomicAdd accumulate =========
        const int cb = bid - COMB_BASE;     // 0..31
        const int kc = cb >> 1;             // K chunk 0..15
        const int m0 = cb & 1;              // 128-row group of j

#pragma unroll
        for (int p = 0; p < 8; p++) {
            int flat = p * 256 + tid;
            int row = flat >> 4;
            int f4 = flat & 15;
            float4 v = *(const float4*)(Wfc1 + (size_t)(m0 * 128 + row) * D_IN + kc * 64 + f4 * 4);
            s16x4 sv;
            sv[0] = f2bf(v.x); sv[1] = f2bf(v.y); sv[2] = f2bf(v.z); sv[3] = f2bf(v.w);
            *(s16x4*)&a_st[row * 72 + f4 * 4] = sv;
        }
        {
            int r = tid >> 2, c0 = tid & 3;
#pragma unroll
            for (int cc = 0; cc < 9; cc++) {
                int col = c0 + cc * 4;
                if (col < 33) {
                    float v = (col < 32) ? Wemb[(size_t)(kc * 64 + r) * 32 + col]
                                         : bemb[kc * 64 + r];
                    wemb_s[r * 33 + col] = v;
                }
            }
        }
        __syncthreads();

        f32x4 acc[2][3];
#pragma unroll
        for (int mt = 0; mt < 2; mt++)
#pragma unroll
            for (int t = 0; t < 3; t++) acc[mt][t] = (f32x4)0.0f;

#pragma unroll
        for (int ks = 0; ks < 2; ks++) {
            s16x8 bv[3];
#pragma unroll
            for (int t = 0; t < 3; t++) {
                int n = t * 16 + nl;
#pragma unroll
                for (int jj = 0; jj < 8; jj++) {
                    float v = (n < 33) ? wemb_s[(ks * 32 + q * 8 + jj) * 33 + n] : 0.0f;
                    bv[t][jj] = f2bf(v);
                }
            }
#pragma unroll
            for (int mt = 0; mt < 2; mt++) {
                s16x8 af = *(const s16x8*)&a_st[(w * 32 + mt * 16 + nl) * 72 + ks * 32 + q * 8];
#pragma unroll
                for (int t = 0; t < 3; t++)
                    acc[mt][t] = __builtin_amdgcn_mfma_f32_16x16x32_bf16(af, bv[t], acc[mt][t], 0, 0, 0);
            }
        }
#pragma unroll
        for (int mt = 0; mt < 2; mt++)
#pragma unroll
            for (int t = 0; t < 3; t++)
#pragma unroll
                for (int r = 0; r < 4; r++) {
                    int j = m0 * 128 + w * 32 + mt * 16 + q * 4 + r;
                    int n = t * 16 + nl;
                    if (n < 32) atomicAdd(&WcombT[j * 32 + n], acc[mt][t][r]);
                    else if (n == 32) atomicAdd(&cbv[j], acc[mt][t][r]);
                }
    } else {
        // ================= end-flag key rows =================
        const int k = tid & 31, b0 = tid >> 5;
        short evk = f2bf(endv[k]);
        for (int b = b0; b < BB_; b += 8)
            pkbf[((size_t)b * NP1 + 512) * 32 + k] = evk;
    }
}

// ---------------------------------------------------------------------------
// K2 back-end, grid 256 x 512. Round-6 structure + latency fixes:
//   - LSTM: h broadcast read from h_all (LDS, same-address broadcast) instead
//     of 32 shfls in the dependent chain; dual accumulators.
//   - logits: all pkbf fragments + masks prefetched to registers up-front.
//   - A/B/D/emb_out: dual accumulators halve the fmaf dep chains.
// ---------------------------------------------------------------------------
__global__ __launch_bounds__(512, 1) void back_kernel(
    const short* __restrict__ pkbf, const float* __restrict__ act_pre0,
    const int* __restrict__ sel, const float* __restrict__ avail,
    const float* __restrict__ Wfc2, const float* __restrict__ bfc2,
    const float* __restrict__ Wih, const float* __restrict__ bih,
    const float* __restrict__ bhh, const float* __restrict__ Whh,
    const float* __restrict__ WcombT, const float* __restrict__ cbv,
    const float* __restrict__ emb0, const float* __restrict__ Wemb,
    const float* __restrict__ bemb,
    float* __restrict__ logits, float* __restrict__ emb_out)
{
    __shared__ float S[19204];
    __shared__ int sel_l[SS_];
    float* rap_l  = S;                    // 8580 (33*260)           [phase A-B]
    float* red_l  = S + 8580;             // 8448 (33*256)           [phase B-C]
    float* x_l    = S + 17028;            // 1056                    [P1 scratch, C-D]
    float* cumE_l = S + 18084;            // 1056
    float* ssel_l = S + 19140;            // 32
    float* xg_l   = S;                    // 4224, overlays rap (dead post-B)
    float* h_all  = S + 4224;             // 1056, overlays rap tail
    float* m0_l   = S + 8580;             // 513, overlays red (dead post-C)
    int*   tf_l   = (int*)(S + 9093);     // 513

    const int tid = threadIdx.x;
    const int b = blockIdx.x;
    const int lane = tid & 63, w = tid >> 6;       // w: 0..7
    const int nl = lane & 15, q = lane >> 4;

    if (tid < SS_) sel_l[tid] = sel[b * SS_ + tid];

    // ---- P1: cumE prefix over selected keys (both halves duplicate) ----
    {
        const int k = tid & 31, sq = (tid >> 5) & 7;
        const int sq4 = sq * 4;
        int s0 = sel[b * SS_ + sq4 + 0];
        int s1 = sel[b * SS_ + sq4 + 1];
        int s2 = sel[b * SS_ + sq4 + 2];
        int s3 = sel[b * SS_ + sq4 + 3];
        float v0 = bf2f(pkbf[((size_t)b * NP1 + s0) * 32 + k]) * INV_N;
        float v1 = bf2f(pkbf[((size_t)b * NP1 + s1) * 32 + k]) * INV_N;
        float v2 = bf2f(pkbf[((size_t)b * NP1 + s2) * 32 + k]) * INV_N;
        float v3 = bf2f(pkbf[((size_t)b * NP1 + s3) * 32 + k]) * INV_N;
        float p0 = v0, p1 = p0 + v1, p2 = p1 + v2, p3 = p2 + v3;
        x_l[sq * 32 + k] = p3;
        __syncthreads();
        float off = 0.0f;
        for (int p = 0; p < 8; p++) if (p < sq) off += x_l[p * 32 + k];
        cumE_l[(sq4 + 1) * 32 + k] = off + p0;
        cumE_l[(sq4 + 2) * 32 + k] = off + p1;
        cumE_l[(sq4 + 3) * 32 + k] = off + p2;
        cumE_l[(sq4 + 4) * 32 + k] = off + p3;
        if (tid < 32) cumE_l[tid] = 0.0f;
        if (sq == 7) ssel_l[k] = off + p3;
    }
    __syncthreads();

    // ---- Phase A: rap[t][j], 2-way t-split, dual accumulators ----
    {
        const int j = tid & 255, half = tid >> 8;
        float wcr[32];
#pragma unroll
        for (int k4 = 0; k4 < 8; k4++) {
            float4 v = *(const float4*)(WcombT + (size_t)j * 32 + k4 * 4);
            wcr[k4*4] = v.x; wcr[k4*4+1] = v.y; wcr[k4*4+2] = v.z; wcr[k4*4+3] = v.w;
        }
        const float cbr = cbv[j];
        const float ap0v = act_pre0[b * 256 + j];
        for (int t = half; t < SP1; t += 2) {
            float ap = fmaf((float)t, cbr, ap0v), apb = 0.0f;
            const float4* ce = (const float4*)&cumE_l[t * 32];
#pragma unroll
            for (int k4 = 0; k4 < 8; k4++) {
                float4 e = ce[k4];
                ap  = fmaf(e.x, wcr[k4*4], ap);   apb = fmaf(e.y, wcr[k4*4+1], apb);
                ap  = fmaf(e.z, wcr[k4*4+2], ap); apb = fmaf(e.w, wcr[k4*4+3], apb);
            }
            rap_l[t * 260 + j] = fmaxf(ap + apb, 0.0f);
        }
    }
    __syncthreads();

    // ---- Phase B: fc2 partials, 2-way t-split, dual accumulators ----
    {
        const int i = tid & 31, seg = (tid >> 5) & 7, half = tid >> 8;
        float wfc2r[32];
#pragma unroll
        for (int i4 = 0; i4 < 8; i4++) {
            float4 v = *(const float4*)(Wfc2 + (size_t)i * 256 + seg * 32 + i4 * 4);
            wfc2r[i4*4] = v.x; wfc2r[i4*4+1] = v.y; wfc2r[i4*4+2] = v.z; wfc2r[i4*4+3] = v.w;
        }
        for (int t = half; t < SP1; t += 2) {
            float pa = 0.0f, pb = 0.0f;
            const float4* rp = (const float4*)&rap_l[t * 260 + seg * 32];
#pragma unroll
            for (int i4 = 0; i4 < 8; i4++) {
                float4 rv = rp[i4];
                pa = fmaf(rv.x, wfc2r[i4*4], pa);   pb = fmaf(rv.y, wfc2r[i4*4+1], pb);
                pa = fmaf(rv.z, wfc2r[i4*4+2], pa); pb = fmaf(rv.w, wfc2r[i4*4+3], pb);
            }
            red_l[t * 256 + seg * 32 + i] = pa + pb;
        }
    }
    __syncthreads();

    // ---- Phase C: reduce -> x ----
    for (int p = 0; p < 3; p++) {
        int idx = p * 512 + tid;
        if (idx < SP1 * 32) {
            int t = idx >> 5, i = idx & 31;
            float x = bfc2[i];
#pragma unroll
            for (int s = 0; s < 8; s++) x += red_l[t * 256 + s * 32 + i];
            x_l[t * 32 + i] = x;
        }
    }
    __syncthreads();

    // ---- Phase D: gates pre-h -> xg (overlays rap), 4-way t-split ----
    {
        const int g = tid & 127, qtr = tid >> 7;     // qtr: 0..3
        float wihr[32];
#pragma unroll
        for (int k4 = 0; k4 < 8; k4++) {
            float4 v = *(const float4*)(Wih + (size_t)g * 32 + k4 * 4);
            wihr[k4*4] = v.x; wihr[k4*4+1] = v.y; wihr[k4*4+2] = v.z; wihr[k4*4+3] = v.w;
        }
        const float bihg = bih[g] + bhh[g];
        for (int t = qtr; t < SP1; t += 4) {
            float ga = bihg, gb = 0.0f;
            const float4* xp = (const float4*)&x_l[t * 32];
#pragma unroll
            for (int k4 = 0; k4 < 8; k4++) {
                float4 xv = xp[k4];
                ga = fmaf(xv.x, wihr[k4*4], ga);   gb = fmaf(xv.y, wihr[k4*4+1], gb);
                ga = fmaf(xv.z, wihr[k4*4+2], ga); gb = fmaf(xv.w, wihr[k4*4+3], gb);
            }
            xg_l[t * 128 + g] = ga + gb;
        }
    }
    __syncthreads();

    // ---- LSTM chain (wave 0, h broadcast via LDS) || mask prep ----
    if (tid < 64) {
        float whh0[32], whh1[32];
#pragma unroll
        for (int k4 = 0; k4 < 8; k4++) {
            float4 v0 = *(const float4*)(Whh + (size_t)tid * 32 + k4 * 4);
            float4 v1 = *(const float4*)(Whh + (size_t)(tid + 64) * 32 + k4 * 4);
            whh0[k4*4] = v0.x; whh0[k4*4+1] = v0.y; whh0[k4*4+2] = v0.z; whh0[k4*4+3] = v0.w;
            whh1[k4*4] = v1.x; whh1[k4*4+1] = v1.y; whh1[k4*4+2] = v1.z; whh1[k4*4+3] = v1.w;
        }
        float c = 0.0f;
        for (int t = 0; t < SP1; ++t) {
            float g0 = xg_l[t * 128 + tid];
            float g1 = xg_l[t * 128 + 64 + tid];
            if (t > 0) {
                // h_{t-1} is in h_all (written by this wave last iteration;
                // same-wave DS ops are in-order). 8 broadcast b128 reads
                // replace 32 shfls inside the dependent chain.
                float hv[32];
#pragma unroll
                for (int k4 = 0; k4 < 8; k4++) {
                    f32x4 v = *(const f32x4*)&h_all[(t - 1) * 32 + k4 * 4];
                    hv[k4*4] = v[0]; hv[k4*4+1] = v[1]; hv[k4*4+2] = v[2]; hv[k4*4+3] = v[3];
                }
                float g0a = 0.0f, g0b = 0.0f, g1a = 0.0f, g1b = 0.0f;
#pragma unroll
                for (int k = 0; k < 32; k += 2) {
                    g0a = fmaf(hv[k], whh0[k], g0a);     g0b = fmaf(hv[k+1], whh0[k+1], g0b);
                    g1a = fmaf(hv[k], whh1[k], g1a);     g1b = fmaf(hv[k+1], whh1[k+1], g1b);
                }
                g0 += g0a + g0b;
                g1 += g1a + g1b;
            }
            float og0 = __shfl_xor(g0, 32);
            float og1 = __shfl_xor(g1, 32);
            float ig = fsig(g0);
            float fg = fsig(og0);
            float gv = ftanh(g1);
            float og = fsig(og1);
            float cn = fg * c + ig * gv;
            float hn = og * ftanh(cn);
            if (tid < 32) {
                c = cn;
                h_all[t * 32 + tid] = hn;
            }
        }
    } else {
        for (int n = tid - 64; n < NP1; n += 448) {
            float m = (n < NN_) ? avail[(size_t)b * NN_ + n] : 1.0f;
            int tf = 1000;
#pragma unroll 8
            for (int s = 0; s < SS_; s++) {
                int sv = sel_l[s];
                if (sv == n) { m = 1.0f; if (s < tf) tf = s; }
            }
            m0_l[n] = m; tf_l[n] = tf;
        }
    }
    __syncthreads();

    // ---- logits via bf16 MFMA (8 waves, tt stride 8, prefetched) ----
    {
        s16x8 afr[3];
#pragma unroll
        for (int mt = 0; mt < 3; mt++) {
            int row = mt * 16 + nl;
            s16x8 av;
#pragma unroll
            for (int jj = 0; jj < 8; jj++) {
                float v = (row < SP1) ? h_all[row * 32 + q * 8 + jj] : 0.0f;
                av[jj] = f2bf(v);
            }
            afr[mt] = av;
        }
        // prefetch all fragments + masks for this wave's tt's up-front
        s16x8 bvr[5]; float m0v[5]; int tfv[5]; bool nvv[5];
#pragma unroll
        for (int ii = 0; ii < 5; ii++) {
            int tt = w + ii * 8;
            int n = tt * 16 + nl;
            bool nv = (tt < 33) && (n < NP1);
            nvv[ii] = nv;
            bvr[ii] = nv ? *(const s16x8*)(pkbf + ((size_t)b * NP1 + n) * 32 + q * 8) : (s16x8)0;
            m0v[ii] = nv ? m0_l[n] : 0.0f;
            tfv[ii] = nv ? tf_l[n] : 0;
        }
#pragma unroll
        for (int ii = 0; ii < 5; ii++) {
            int tt = w + ii * 8;
            if (tt >= 33) break;
            int n = tt * 16 + nl;
            f32x4 acc[3];
#pragma unroll
            for (int mt = 0; mt < 3; mt++)
                acc[mt] = __builtin_amdgcn_mfma_f32_16x16x32_bf16(afr[mt], bvr[ii], (f32x4)0.0f, 0, 0, 0);
#pragma unroll
            for (int mt = 0; mt < 3; mt++)
#pragma unroll
                for (int r = 0; r < 4; r++) {
                    int t = mt * 16 + q * 4 + r;
                    if (t < SP1 && nvv[ii]) {
                        float mv = (t <= tfv[ii]) ? m0v[ii] : 0.0f;
                        logits[((size_t)b * SP1 + t) * NP1 + n] = acc[mt][r] - (1.0f - mv) * 1e9f;
                    }
                }
        }
    }

    // ---- emb_out (dual accumulators) ----
#pragma unroll
    for (int p = 0; p < 2; p++) {
        int i = p * 512 + tid;
        float acca = emb0[(size_t)b * D_IN + i] + 32.0f * bemb[i];
        float accb = 0.0f;
        const float* wr = Wemb + (size_t)i * 32;
#pragma unroll
        for (int k4 = 0; k4 < 8; k4++) {
            float4 wv = *(const float4*)(wr + k4 * 4);
            acca = fmaf(ssel_l[k4*4+0], wv.x, acca);
            accb = fmaf(ssel_l[k4*4+1], wv.y, accb);
            acca = fmaf(ssel_l[k4*4+2], wv.z, acca);
            accb = fmaf(ssel_l[k4*4+3], wv.w, accb);
        }
        emb_out[(size_t)b * D_IN + i] = acca + accb;
    }
}

extern "C" void kernel_launch(void* const* d_in, const int* in_sizes, int n_in,
                              void* d_out, int out_size, void* d_ws, size_t ws_size,
                              hipStream_t stream)
{
    (void)in_sizes; (void)n_in; (void)out_size; (void)ws_size;
    const float* embedding = (const float*)d_in[0];
    const float* atm       = (const float*)d_in[1];
    const float* avail     = (const float*)d_in[2];
    const float* ent       = (const float*)d_in[3];
    const int*   sel       = (const int*)  d_in[4];
    const float* endv      = (const float*)d_in[5];
    const float* Wk   = (const float*)d_in[6];
    const float* bk   = (const float*)d_in[7];
    const float* Wf   = (const float*)d_in[8];
    const float* bf   = (const float*)d_in[9];
    const float* Wfc1 = (const float*)d_in[10];
    const float* bfc1 = (const float*)d_in[11];
    const float* Wfc2 = (const float*)d_in[12];
    const float* bfc2 = (const float*)d_in[13];
    const float* Wemb = (const float*)d_in[14];
    const float* bemb = (const float*)d_in[15];
    const float* Wih  = (const float*)d_in[16];
    const float* bih  = (const float*)d_in[17];
    const float* Whh  = (const float*)d_in[18];
    const float* bhh  = (const float*)d_in[19];

    float* ws = (float*)d_ws;
    float* act_pre = ws;                          // 65536 f
    float* WcombT  = act_pre + BB_ * 256;         // 8192 f
    float* cbv     = WcombT + 256 * 32;           // 256 f
    short* pkbf    = (short*)(cbv + 256);         // 256*513*32 shorts

    float* logits  = (float*)d_out;
    float* emb_out = logits + (size_t)BB_ * SP1 * NP1;

    // zero the comb accumulators (WcombT + cbv are contiguous: 8448 floats)
    hipMemsetAsync(WcombT, 0, (size_t)(256 * 32 + 256) * sizeof(float), stream);

    front_kernel<<<FRONT_GRID, 256, 0, stream>>>(ent, Wk, bk, endv, Wemb, bemb,
                                                 Wfc1, embedding, bfc1, atm, Wf, bf,
                                                 pkbf, WcombT, cbv, act_pre);
    back_kernel<<<BB_, 512, 0, stream>>>(pkbf, act_pre, sel, avail,
                                         Wfc2, bfc2, Wih, bih, bhh, Whh,
                                         WcombT, cbv, embedding, Wemb, bemb,
                                         logits, emb_out);
}

// Round 8
// 284.661 us; speedup vs baseline: 1.1043x; 1.0177x over previous
//
#include <hip/hip_runtime.h>
#include <math.h>

#define BB_ 256
#define NN_ 512
#define SS_ 32
#define NP1 513
#define SP1 33
#define D_IN 1024
#define D_TYPE 259
#define INV_N (1.0f/512.0f)

// front grid layout: [0,256) actpre | [256,288) comb (16 kc x 2 rowgrp) |
//                    288 end | [289, 289+2048) keys
#define N_ACT 256
#define COMB_BASE 256
#define N_COMB 32
#define END_BID 288
#define KEY_BASE 289
#define N_KEY 2048
#define FRONT_GRID (KEY_BASE + N_KEY)

typedef short s16x4 __attribute__((ext_vector_type(4)));
typedef short s16x8 __attribute__((ext_vector_type(8)));
typedef float f32x4 __attribute__((ext_vector_type(4)));

#if defined(__has_builtin)
#if __has_builtin(__builtin_amdgcn_rcpf)
#define FRCP(x) __builtin_amdgcn_rcpf(x)
#else
#define FRCP(x) (1.0f / (x))
#endif
#else
#define FRCP(x) (1.0f / (x))
#endif

__device__ __forceinline__ float fsig(float x) { return FRCP(1.0f + __expf(-x)); }
__device__ __forceinline__ float ftanh(float x) { return fmaf(-2.0f, FRCP(1.0f + __expf(2.0f * x)), 1.0f); }
__device__ __forceinline__ short f2bf(float f) {
    unsigned u = __float_as_uint(f);
    unsigned r = (u + 0x7FFFu + ((u >> 16) & 1u)) >> 16;
    return (short)r;
}
__device__ __forceinline__ float bf2f(short s) {
    unsigned u = ((unsigned)(unsigned short)s) << 16;
    return __uint_as_float(u);
}

// ---------------------------------------------------------------------------
// K1 fused front-end, grid 2337 x 256.
// Keys now use a 4-buffer ZERO-RECYCLE pipeline: all 4 LDS chunk buffers are
// distinct (64KB union), so all 16 global_load_lds issue at t0 and the loop
// is pure {vmcnt(12/8/4/0) + barrier -> compute}. No lgkm drains, no mid-loop
// staging: sustained (not bursty) bytes-in-flight. 2 blocks/CU (LDS-bound).
// ---------------------------------------------------------------------------
__global__ __launch_bounds__(256) void front_kernel(
    const float* __restrict__ ent, const float* __restrict__ Wk,
    const float* __restrict__ bk, const float* __restrict__ endv,
    const float* __restrict__ Wemb, const float* __restrict__ bemb,
    const float* __restrict__ Wfc1, const float* __restrict__ emb0,
    const float* __restrict__ bfc1, const float* __restrict__ atm,
    const float* __restrict__ Wf, const float* __restrict__ bf,
    short* __restrict__ pkbf, float* __restrict__ WcombT,
    float* __restrict__ cbv, float* __restrict__ act_pre)
{
    __shared__ __align__(128) char u_raw[65536];
    short* a_st   = (short*)u_raw;              // comb: 128*72*2 = 18432 B
    float* wemb_s = (float*)(u_raw + 18688);    // comb: 64*33*4  = 8448 B
    float* a_lds  = (float*)u_raw;              // actpre: 16*260*4
    float* w_lds  = (float*)(u_raw + 16640);

    const int tid = threadIdx.x;
    const int bid = blockIdx.x;
    const int lane = tid & 63, w = tid >> 6;
    const int nl = lane & 15, q = lane >> 4;

    if (bid >= KEY_BASE) {
        // ================= key MFMA: 4-buffer zero-recycle pipeline =========
        float* kb = (float*)u_raw;     // [4][64][64] f32
        const size_t rowbase = (size_t)(bid - KEY_BASE) * 64;

#define KSTAGE(kc_) do {                                                          \
        _Pragma("unroll")                                                         \
        for (int p_ = 0; p_ < 4; p_++) {                                          \
            int flat_ = p_ * 256 + tid;                                           \
            int row_ = flat_ >> 4, u_ = flat_ & 15;                               \
            int gf4_ = (u_ & 8) | ((u_ ^ row_) & 7);                              \
            const float* src_ = ent + (((rowbase + (size_t)row_) << 8)            \
                                       + (kc_) * 64 + gf4_ * 4);                  \
            char* dst_ = u_raw + (kc_) * 16384 + ((p_ << 8) + (w << 6)) * 16;     \
            __builtin_amdgcn_global_load_lds(                                     \
                (const __attribute__((address_space(1))) void*)src_,              \
                (__attribute__((address_space(3))) void*)dst_, 16, 0, 0);         \
        }                                                                         \
    } while (0)

        // issue the entire tile: 16 loads in flight per thread, never recycled
        KSTAGE(0);
        KSTAGE(1);
        KSTAGE(2);
        KSTAGE(3);

        // B fragments (Wk, L2-hot) load+convert overlaps the stage latency;
        // the f2bf consumption forces the B-load drain, so the vmcnt counts
        // below see exactly the 16 staging loads.
        s16x8 bfr[8][2];
#pragma unroll
        for (int s = 0; s < 8; s++)
#pragma unroll
            for (int t = 0; t < 2; t++) {
                const float* src = Wk + (size_t)(t * 16 + nl) * 256 + s * 32 + q * 8;
                float4 v0 = *(const float4*)(src);
                float4 v1 = *(const float4*)(src + 4);
                s16x8 bv;
                bv[0] = f2bf(v0.x); bv[1] = f2bf(v0.y); bv[2] = f2bf(v0.z); bv[3] = f2bf(v0.w);
                bv[4] = f2bf(v1.x); bv[5] = f2bf(v1.y); bv[6] = f2bf(v1.z); bv[7] = f2bf(v1.w);
                bfr[s][t] = bv;
            }

        f32x4 acc[2];
        acc[0] = (f32x4)0.0f; acc[1] = (f32x4)0.0f;

        const int rl = w * 16 + nl;     // this lane's A row (0..63)
        const int rx = rl & 7;          // swizzle key

#define KWAIT(n_) do {                                                            \
        asm volatile("s_waitcnt vmcnt(" #n_ ")" ::: "memory");                    \
        __builtin_amdgcn_s_barrier();                                             \
        asm volatile("" ::: "memory");                                            \
    } while (0)
#define KCOMPUTE(kc_) do {                                                        \
        const float* kbc = kb + (kc_) * 4096;                                     \
        _Pragma("unroll")                                                         \
        for (int ks = 0; ks < 2; ks++) {                                          \
            int s0 = ks * 8 + ((q * 2) ^ rx);                                     \
            int s1 = ks * 8 + ((q * 2 + 1) ^ rx);                                 \
            f32x4 a0 = *(const f32x4*)&kbc[rl * 64 + s0 * 4];                     \
            f32x4 a1 = *(const f32x4*)&kbc[rl * 64 + s1 * 4];                     \
            s16x8 af;                                                             \
            af[0] = f2bf(a0[0]); af[1] = f2bf(a0[1]);                             \
            af[2] = f2bf(a0[2]); af[3] = f2bf(a0[3]);                             \
            af[4] = f2bf(a1[0]); af[5] = f2bf(a1[1]);                             \
            af[6] = f2bf(a1[2]); af[7] = f2bf(a1[3]);                             \
            acc[0] = __builtin_amdgcn_mfma_f32_16x16x32_bf16(                     \
                af, bfr[(kc_) * 2 + ks][0], acc[0], 0, 0, 0);                     \
            acc[1] = __builtin_amdgcn_mfma_f32_16x16x32_bf16(                     \
                af, bfr[(kc_) * 2 + ks][1], acc[1], 0, 0, 0);                     \
        }                                                                         \
    } while (0)

        KWAIT(12); KCOMPUTE(0);
        KWAIT(8);  KCOMPUTE(1);
        KWAIT(4);  KCOMPUTE(2);
        KWAIT(0);  KCOMPUTE(3);

#undef KCOMPUTE
#undef KWAIT
#undef KSTAGE

        float bkv0 = bk[nl], bkv1 = bk[16 + nl];
#pragma unroll
        for (int t = 0; t < 2; t++)
#pragma unroll
            for (int r = 0; r < 4; r++) {
                int rowg = (int)rowbase + w * 16 + q * 4 + r;
                int b = rowg >> 9, n = rowg & 511;
                pkbf[((size_t)b * NP1 + n) * 32 + t * 16 + nl] =
                    f2bf(acc[t][r] + (t ? bkv1 : bkv0));
            }
    } else if (bid < N_ACT) {
        // ================= actpre =================
        const int idx = bid;
        const int jt = idx & 15, bt = idx >> 4;
        const int bb = tid >> 4, jj = tid & 15;

#pragma unroll 4
        for (int r = 0; r < 16; r++) {
            a_lds[r * 260 + tid] = atm[(size_t)(bt * 16 + r) * D_TYPE + tid];
            w_lds[r * 260 + tid] = Wf[(size_t)(jt * 16 + r) * D_TYPE + tid];
            if (tid < 3) {
                a_lds[r * 260 + 256 + tid] = atm[(size_t)(bt * 16 + r) * D_TYPE + 256 + tid];
                w_lds[r * 260 + 256 + tid] = Wf[(size_t)(jt * 16 + r) * D_TYPE + 256 + tid];
            }
        }
        __syncthreads();
        float accf;
        {
            float f0 = 0.0f, f1 = 0.0f, f2 = 0.0f, f3 = 0.0f;
            const float4* ap = (const float4*)&a_lds[bb * 260];
            const float4* wp = (const float4*)&w_lds[jj * 260];
#pragma unroll 8
            for (int i4 = 0; i4 < 64; i4++) {
                float4 a = ap[i4]; float4 wv = wp[i4];
                f0 = fmaf(a.x, wv.x, f0); f1 = fmaf(a.y, wv.y, f1);
                f2 = fmaf(a.z, wv.z, f2); f3 = fmaf(a.w, wv.w, f3);
            }
            accf = (f0 + f1) + (f2 + f3);
            for (int i = 256; i < 259; i++) accf = fmaf(a_lds[bb * 260 + i], w_lds[jj * 260 + i], accf);
        }
        float c0 = 0.0f, c1 = 0.0f, c2 = 0.0f, c3 = 0.0f;
        for (int c = 0; c < 4; c++) {
            __syncthreads();
#pragma unroll
            for (int p = 0; p < 4; p++) {
                int l4 = p * 256 + tid;
                int r = l4 >> 6, k4 = l4 & 63;
                *(float4*)&a_lds[r * 260 + k4 * 4] =
                    *(const float4*)(emb0 + (size_t)(bt * 16 + r) * D_IN + c * 256 + k4 * 4);
                *(float4*)&w_lds[r * 260 + k4 * 4] =
                    *(const float4*)(Wfc1 + (size_t)(jt * 16 + r) * D_IN + c * 256 + k4 * 4);
            }
            __syncthreads();
#pragma unroll 8
            for (int k4 = 0; k4 < 64; k4++) {
                float4 a = *(const float4*)&a_lds[bb * 260 + k4 * 4];
                float4 wv = *(const float4*)&w_lds[jj * 260 + k4 * 4];
                c0 = fmaf(a.x, wv.x, c0); c1 = fmaf(a.y, wv.y, c1);
                c2 = fmaf(a.z, wv.z, c2); c3 = fmaf(a.w, wv.w, c3);
            }
        }
        float acc = (c0 + c1) + (c2 + c3);
        const int b = bt * 16 + bb, j = jt * 16 + jj;
        act_pre[b * 256 + j] = acc + bfc1[j] + fmaxf(accf + bf[j], 0.0f);
    } else if (bid < END_BID) {
        // ========= comb partial: ONE kc chunk, atomicAdd accumulate =========
        const int cb = bid - COMB_BASE;     // 0..31
        const int kc = cb >> 1;             // K chunk 0..15
        const int m0 = cb & 1;              // 128-row group of j

#pragma unroll
        for (int p = 0; p < 8; p++) {
            int flat = p * 256 + tid;
            int row = flat >> 4;
            int f4 = flat & 15;
            float4 v = *(const float4*)(Wfc1 + (size_t)(m0 * 128 + row) * D_IN + kc * 64 + f4 * 4);
            s16x4 sv;
            sv[0] = f2bf(v.x); sv[1] = f2bf(v.y); sv[2] = f2bf(v.z); sv[3] = f2bf(v.w);
            *(s16x4*)&a_st[row * 72 + f4 * 4] = sv;
        }
        {
            int r = tid >> 2, c0 = tid & 3;
#pragma unroll
            for (int cc = 0; cc < 9; cc++) {
                int col = c0 + cc * 4;
                if (col < 33) {
                    float v = (col < 32) ? Wemb[(size_t)(kc * 64 + r) * 32 + col]
                                         : bemb[kc * 64 + r];
                    wemb_s[r * 33 + col] = v;
                }
            }
        }
        __syncthreads();

        f32x4 acc[2][3];
#pragma unroll
        for (int mt = 0; mt < 2; mt++)
#pragma unroll
            for (int t = 0; t < 3; t++) acc[mt][t] = (f32x4)0.0f;

#pragma unroll
        for (int ks = 0; ks < 2; ks++) {
            s16x8 bv[3];
#pragma unroll
            for (int t = 0; t < 3; t++) {
                int n = t * 16 + nl;
#pragma unroll
                for (int jj = 0; jj < 8; jj++) {
                    float v = (n < 33) ? wemb_s[(ks * 32 + q * 8 + jj) * 33 + n] : 0.0f;
                    bv[t][jj] = f2bf(v);
                }
            }
#pragma unroll
            for (int mt = 0; mt < 2; mt++) {
                s16x8 af = *(const s16x8*)&a_st[(w * 32 + mt * 16 + nl) * 72 + ks * 32 + q * 8];
#pragma unroll
                for (int t = 0; t < 3; t++)
                    acc[mt][t] = __builtin_amdgcn_mfma_f32_16x16x32_bf16(af, bv[t], acc[mt][t], 0, 0, 0);
            }
        }
#pragma unroll
        for (int mt = 0; mt < 2; mt++)
#pragma unroll
            for (int t = 0; t < 3; t++)
#pragma unroll
                for (int r = 0; r < 4; r++) {
                    int j = m0 * 128 + w * 32 + mt * 16 + q * 4 + r;
                    int n = t * 16 + nl;
                    if (n < 32) atomicAdd(&WcombT[j * 32 + n], acc[mt][t][r]);
                    else if (n == 32) atomicAdd(&cbv[j], acc[mt][t][r]);
                }
    } else {
        // ================= end-flag key rows =================
        const int k = tid & 31, b0 = tid >> 5;
        short evk = f2bf(endv[k]);
        for (int b = b0; b < BB_; b += 8)
            pkbf[((size_t)b * NP1 + 512) * 32 + k] = evk;
    }
}

// ---------------------------------------------------------------------------
// K2 back-end, grid 256 x 512 (round-7 verified).
// ---------------------------------------------------------------------------
__global__ __launch_bounds__(512, 1) void back_kernel(
    const short* __restrict__ pkbf, const float* __restrict__ act_pre0,
    const int* __restrict__ sel, const float* __restrict__ avail,
    const float* __restrict__ Wfc2, const float* __restrict__ bfc2,
    const float* __restrict__ Wih, const float* __restrict__ bih,
    const float* __restrict__ bhh, const float* __restrict__ Whh,
    const float* __restrict__ WcombT, const float* __restrict__ cbv,
    const float* __restrict__ emb0, const float* __restrict__ Wemb,
    const float* __restrict__ bemb,
    float* __restrict__ logits, float* __restrict__ emb_out)
{
    __shared__ float S[19204];
    __shared__ int sel_l[SS_];
    float* rap_l  = S;                    // 8580 (33*260)           [phase A-B]
    float* red_l  = S + 8580;             // 8448 (33*256)           [phase B-C]
    float* x_l    = S + 17028;            // 1056                    [P1 scratch, C-D]
    float* cumE_l = S + 18084;            // 1056
    float* ssel_l = S + 19140;            // 32
    float* xg_l   = S;                    // 4224, overlays rap (dead post-B)
    float* h_all  = S + 4224;             // 1056, overlays rap tail
    float* m0_l   = S + 8580;             // 513, overlays red (dead post-C)
    int*   tf_l   = (int*)(S + 9093);     // 513

    const int tid = threadIdx.x;
    const int b = blockIdx.x;
    const int lane = tid & 63, w = tid >> 6;       // w: 0..7
    const int nl = lane & 15, q = lane >> 4;

    if (tid < SS_) sel_l[tid] = sel[b * SS_ + tid];

    // ---- P1: cumE prefix over selected keys (both halves duplicate) ----
    {
        const int k = tid & 31, sq = (tid >> 5) & 7;
        const int sq4 = sq * 4;
        int s0 = sel[b * SS_ + sq4 + 0];
        int s1 = sel[b * SS_ + sq4 + 1];
        int s2 = sel[b * SS_ + sq4 + 2];
        int s3 = sel[b * SS_ + sq4 + 3];
        float v0 = bf2f(pkbf[((size_t)b * NP1 + s0) * 32 + k]) * INV_N;
        float v1 = bf2f(pkbf[((size_t)b * NP1 + s1) * 32 + k]) * INV_N;
        float v2 = bf2f(pkbf[((size_t)b * NP1 + s2) * 32 + k]) * INV_N;
        float v3 = bf2f(pkbf[((size_t)b * NP1 + s3) * 32 + k]) * INV_N;
        float p0 = v0, p1 = p0 + v1, p2 = p1 + v2, p3 = p2 + v3;
        x_l[sq * 32 + k] = p3;
        __syncthreads();
        float off = 0.0f;
        for (int p = 0; p < 8; p++) if (p < sq) off += x_l[p * 32 + k];
        cumE_l[(sq4 + 1) * 32 + k] = off + p0;
        cumE_l[(sq4 + 2) * 32 + k] = off + p1;
        cumE_l[(sq4 + 3) * 32 + k] = off + p2;
        cumE_l[(sq4 + 4) * 32 + k] = off + p3;
        if (tid < 32) cumE_l[tid] = 0.0f;
        if (sq == 7) ssel_l[k] = off + p3;
    }
    __syncthreads();

    // ---- Phase A: rap[t][j], 2-way t-split, dual accumulators ----
    {
        const int j = tid & 255, half = tid >> 8;
        float wcr[32];
#pragma unroll
        for (int k4 = 0; k4 < 8; k4++) {
            float4 v = *(const float4*)(WcombT + (size_t)j * 32 + k4 * 4);
            wcr[k4*4] = v.x; wcr[k4*4+1] = v.y; wcr[k4*4+2] = v.z; wcr[k4*4+3] = v.w;
        }
        const float cbr = cbv[j];
        const float ap0v = act_pre0[b * 256 + j];
        for (int t = half; t < SP1; t += 2) {
            float ap = fmaf((float)t, cbr, ap0v), apb = 0.0f;
            const float4* ce = (const float4*)&cumE_l[t * 32];
#pragma unroll
            for (int k4 = 0; k4 < 8; k4++) {
                float4 e = ce[k4];
                ap  = fmaf(e.x, wcr[k4*4], ap);   apb = fmaf(e.y, wcr[k4*4+1], apb);
                ap  = fmaf(e.z, wcr[k4*4+2], ap); apb = fmaf(e.w, wcr[k4*4+3], apb);
            }
            rap_l[t * 260 + j] = fmaxf(ap + apb, 0.0f);
        }
    }
    __syncthreads();

    // ---- Phase B: fc2 partials, 2-way t-split, dual accumulators ----
    {
        const int i = tid & 31, seg = (tid >> 5) & 7, half = tid >> 8;
        float wfc2r[32];
#pragma unroll
        for (int i4 = 0; i4 < 8; i4++) {
            float4 v = *(const float4*)(Wfc2 + (size_t)i * 256 + seg * 32 + i4 * 4);
            wfc2r[i4*4] = v.x; wfc2r[i4*4+1] = v.y; wfc2r[i4*4+2] = v.z; wfc2r[i4*4+3] = v.w;
        }
        for (int t = half; t < SP1; t += 2) {
            float pa = 0.0f, pb = 0.0f;
            const float4* rp = (const float4*)&rap_l[t * 260 + seg * 32];
#pragma unroll
            for (int i4 = 0; i4 < 8; i4++) {
                float4 rv = rp[i4];
                pa = fmaf(rv.x, wfc2r[i4*4], pa);   pb = fmaf(rv.y, wfc2r[i4*4+1], pb);
                pa = fmaf(rv.z, wfc2r[i4*4+2], pa); pb = fmaf(rv.w, wfc2r[i4*4+3], pb);
            }
            red_l[t * 256 + seg * 32 + i] = pa + pb;
        }
    }
    __syncthreads();

    // ---- Phase C: reduce -> x ----
    for (int p = 0; p < 3; p++) {
        int idx = p * 512 + tid;
        if (idx < SP1 * 32) {
            int t = idx >> 5, i = idx & 31;
            float x = bfc2[i];
#pragma unroll
            for (int s = 0; s < 8; s++) x += red_l[t * 256 + s * 32 + i];
            x_l[t * 32 + i] = x;
        }
    }
    __syncthreads();

    // ---- Phase D: gates pre-h -> xg (overlays rap), 4-way t-split ----
    {
        const int g = tid & 127, qtr = tid >> 7;     // qtr: 0..3
        float wihr[32];
#pragma unroll
        for (int k4 = 0; k4 < 8; k4++) {
            float4 v = *(const float4*)(Wih + (size_t)g * 32 + k4 * 4);
            wihr[k4*4] = v.x; wihr[k4*4+1] = v.y; wihr[k4*4+2] = v.z; wihr[k4*4+3] = v.w;
        }
        const float bihg = bih[g] + bhh[g];
        for (int t = qtr; t < SP1; t += 4) {
            float ga = bihg, gb = 0.0f;
            const float4* xp = (const float4*)&x_l[t * 32];
#pragma unroll
            for (int k4 = 0; k4 < 8; k4++) {
                float4 xv = xp[k4];
                ga = fmaf(xv.x, wihr[k4*4], ga);   gb = fmaf(xv.y, wihr[k4*4+1], gb);
                ga = fmaf(xv.z, wihr[k4*4+2], ga); gb = fmaf(xv.w, wihr[k4*4+3], gb);
            }
            xg_l[t * 128 + g] = ga + gb;
        }
    }
    __syncthreads();

    // ---- LSTM chain (wave 0, h broadcast via LDS) || mask prep ----
    if (tid < 64) {
        float whh0[32], whh1[32];
#pragma unroll
        for (int k4 = 0; k4 < 8; k4++) {
            float4 v0 = *(const float4*)(Whh + (size_t)tid * 32 + k4 * 4);
            float4 v1 = *(const float4*)(Whh + (size_t)(tid + 64) * 32 + k4 * 4);
            whh0[k4*4] = v0.x; whh0[k4*4+1] = v0.y; whh0[k4*4+2] = v0.z; whh0[k4*4+3] = v0.w;
            whh1[k4*4] = v1.x; whh1[k4*4+1] = v1.y; whh1[k4*4+2] = v1.z; whh1[k4*4+3] = v1.w;
        }
        float c = 0.0f;
        for (int t = 0; t < SP1; ++t) {
            float g0 = xg_l[t * 128 + tid];
            float g1 = xg_l[t * 128 + 64 + tid];
            if (t > 0) {
                float hv[32];
#pragma unroll
                for (int k4 = 0; k4 < 8; k4++) {
                    f32x4 v = *(const f32x4*)&h_all[(t - 1) * 32 + k4 * 4];
                    hv[k4*4] = v[0]; hv[k4*4+1] = v[1]; hv[k4*4+2] = v[2]; hv[k4*4+3] = v[3];
                }
                float g0a = 0.0f, g0b = 0.0f, g1a = 0.0f, g1b = 0.0f;
#pragma unroll
                for (int k = 0; k < 32; k += 2) {
                    g0a = fmaf(hv[k], whh0[k], g0a);     g0b = fmaf(hv[k+1], whh0[k+1], g0b);
                    g1a = fmaf(hv[k], whh1[k], g1a);     g1b = fmaf(hv[k+1], whh1[k+1], g1b);
                }
                g0 += g0a + g0b;
                g1 += g1a + g1b;
            }
            float og0 = __shfl_xor(g0, 32);
            float og1 = __shfl_xor(g1, 32);
            float ig = fsig(g0);
            float fg = fsig(og0);
            float gv = ftanh(g1);
            float og = fsig(og1);
            float cn = fg * c + ig * gv;
            float hn = og * ftanh(cn);
            if (tid < 32) {
                c = cn;
                h_all[t * 32 + tid] = hn;
            }
        }
    } else {
        for (int n = tid - 64; n < NP1; n += 448) {
            float m = (n < NN_) ? avail[(size_t)b * NN_ + n] : 1.0f;
            int tf = 1000;
#pragma unroll 8
            for (int s = 0; s < SS_; s++) {
                int sv = sel_l[s];
                if (sv == n) { m = 1.0f; if (s < tf) tf = s; }
            }
            m0_l[n] = m; tf_l[n] = tf;
        }
    }
    __syncthreads();

    // ---- logits via bf16 MFMA (8 waves, tt stride 8, prefetched) ----
    {
        s16x8 afr[3];
#pragma unroll
        for (int mt = 0; mt < 3; mt++) {
            int row = mt * 16 + nl;
            s16x8 av;
#pragma unroll
            for (int jj = 0; jj < 8; jj++) {
                float v = (row < SP1) ? h_all[row * 32 + q * 8 + jj] : 0.0f;
                av[jj] = f2bf(v);
            }
            afr[mt] = av;
        }
        s16x8 bvr[5]; float m0v[5]; int tfv[5]; bool nvv[5];
#pragma unroll
        for (int ii = 0; ii < 5; ii++) {
            int tt = w + ii * 8;
            int n = tt * 16 + nl;
            bool nv = (tt < 33) && (n < NP1);
            nvv[ii] = nv;
            bvr[ii] = nv ? *(const s16x8*)(pkbf + ((size_t)b * NP1 + n) * 32 + q * 8) : (s16x8)0;
            m0v[ii] = nv ? m0_l[n] : 0.0f;
            tfv[ii] = nv ? tf_l[n] : 0;
        }
#pragma unroll
        for (int ii = 0; ii < 5; ii++) {
            int tt = w + ii * 8;
            if (tt >= 33) break;
            int n = tt * 16 + nl;
            f32x4 acc[3];
#pragma unroll
            for (int mt = 0; mt < 3; mt++)
                acc[mt] = __builtin_amdgcn_mfma_f32_16x16x32_bf16(afr[mt], bvr[ii], (f32x4)0.0f, 0, 0, 0);
#pragma unroll
            for (int mt = 0; mt < 3; mt++)
#pragma unroll
                for (int r = 0; r < 4; r++) {
                    int t = mt * 16 + q * 4 + r;
                    if (t < SP1 && nvv[ii]) {
                        float mv = (t <= tfv[ii]) ? m0v[ii] : 0.0f;
                        logits[((size_t)b * SP1 + t) * NP1 + n] = acc[mt][r] - (1.0f - mv) * 1e9f;
                    }
                }
        }
    }

    // ---- emb_out (dual accumulators) ----
#pragma unroll
    for (int p = 0; p < 2; p++) {
        int i = p * 512 + tid;
        float acca = emb0[(size_t)b * D_IN + i] + 32.0f * bemb[i];
        float accb = 0.0f;
        const float* wr = Wemb + (size_t)i * 32;
#pragma unroll
        for (int k4 = 0; k4 < 8; k4++) {
            float4 wv = *(const float4*)(wr + k4 * 4);
            acca = fmaf(ssel_l[k4*4+0], wv.x, acca);
            accb = fmaf(ssel_l[k4*4+1], wv.y, accb);
            acca = fmaf(ssel_l[k4*4+2], wv.z, acca);
            accb = fmaf(ssel_l[k4*4+3], wv.w, accb);
        }
        emb_out[(size_t)b * D_IN + i] = acca + accb;
    }
}

extern "C" void kernel_launch(void* const* d_in, const int* in_sizes, int n_in,
                              void* d_out, int out_size, void* d_ws, size_t ws_size,
                              hipStream_t stream)
{
    (void)in_sizes; (void)n_in; (void)out_size; (void)ws_size;
    const float* embedding = (const float*)d_in[0];
    const float* atm       = (const float*)d_in[1];
    const float* avail     = (const float*)d_in[2];
    const float* ent       = (const float*)d_in[3];
    const int*   sel       = (const int*)  d_in[4];
    const float* endv      = (const float*)d_in[5];
    const float* Wk   = (const float*)d_in[6];
    const float* bk   = (const float*)d_in[7];
    const float* Wf   = (const float*)d_in[8];
    const float* bf   = (const float*)d_in[9];
    const float* Wfc1 = (const float*)d_in[10];
    const float* bfc1 = (const float*)d_in[11];
    const float* Wfc2 = (const float*)d_in[12];
    const float* bfc2 = (const float*)d_in[13];
    const float* Wemb = (const float*)d_in[14];
    const float* bemb = (const float*)d_in[15];
    const float* Wih  = (const float*)d_in[16];
    const float* bih  = (const float*)d_in[17];
    const float* Whh  = (const float*)d_in[18];
    const float* bhh  = (const float*)d_in[19];

    float* ws = (float*)d_ws;
    float* act_pre = ws;                          // 65536 f
    float* WcombT  = act_pre + BB_ * 256;         // 8192 f
    float* cbv     = WcombT + 256 * 32;           // 256 f
    short* pkbf    = (short*)(cbv + 256);         // 256*513*32 shorts

    float* logits  = (float*)d_out;
    float* emb_out = logits + (size_t)BB_ * SP1 * NP1;

    // zero the comb accumulators (WcombT + cbv are contiguous: 8448 floats)
    hipMemsetAsync(WcombT, 0, (size_t)(256 * 32 + 256) * sizeof(float), stream);

    front_kernel<<<FRONT_GRID, 256, 0, stream>>>(ent, Wk, bk, endv, Wemb, bemb,
                                                 Wfc1, embedding, bfc1, atm, Wf, bf,
                                                 pkbf, WcombT, cbv, act_pre);
    back_kernel<<<BB_, 512, 0, stream>>>(pkbf, act_pre, sel, avail,
                                         Wfc2, bfc2, Wih, bih, bhh, Whh,
                                         WcombT, cbv, embedding, Wemb, bemb,
                                         logits, emb_out);
}